// Round 2
// baseline (6862.463 us; speedup 1.0000x reference)
//
#include <hip/hip_runtime.h>

#define D_MODEL 1024
#define N_HEADS 16
#define DH 64
#define N_LAYERS 4
#define N_LEVELS 8
#define BB 2
#define TT 1024
#define MM (BB*TT)
#define EPSV 1e-5f

typedef float f32x4 __attribute__((ext_vector_type(4)));
typedef short bf16x8 __attribute__((ext_vector_type(8)));

__device__ __forceinline__ float bf2f(unsigned short u) {
    union { unsigned int i; float f; } c; c.i = ((unsigned int)u) << 16; return c.f;
}
__device__ __forceinline__ unsigned short f2bf(float f) {
    union { float f; unsigned int i; } c; c.f = f;
    unsigned int x = c.i;
    return (unsigned short)((x + 0x7fffu + ((x >> 16) & 1u)) >> 16);  // RNE
}

// ---- dtype detection: even u16 halves of an fp32 stream are uniform mantissa
// bits (~12% land in bf16-exponent band); of a bf16 stream ~100% structured.
__global__ void detect_kernel(const unsigned short* __restrict__ x, int* __restrict__ flag) {
    __shared__ int cnts[256];
    int cnt = 0;
    for (int i = threadIdx.x; i < 16384; i += 256) {
        unsigned short u = x[2 * i];
        int e = (u >> 7) & 0xFF;
        if (e >= 110 && e <= 140) cnt++;
    }
    cnts[threadIdx.x] = cnt;
    __syncthreads();
    for (int s = 128; s; s >>= 1) {
        if (threadIdx.x < s) cnts[threadIdx.x] += cnts[threadIdx.x + s];
        __syncthreads();
    }
    if (threadIdx.x == 0) flag[0] = (cnts[0] > 12000) ? 1 : 0;  // 1 = inputs are bf16
}

// ---- converters ----
__global__ void load_f32_kernel(const void* __restrict__ src, float* __restrict__ dst,
                                const int* __restrict__ flag, int n) {
    int i = blockIdx.x * 256 + threadIdx.x;
    if (i >= n) return;
    dst[i] = flag[0] ? bf2f(((const unsigned short*)src)[i]) : ((const float*)src)[i];
}
__global__ void load_bf16_off_kernel(const void* __restrict__ src, unsigned short* __restrict__ dst,
                                     const int* __restrict__ flag, int n, long long off) {
    int i = blockIdx.x * 256 + threadIdx.x;
    if (i >= n) return;
    long long j = off + i;
    dst[i] = flag[0] ? ((const unsigned short*)src)[j] : f2bf(((const float*)src)[j]);
}
__global__ void store_out_kernel(const float* __restrict__ src, void* __restrict__ dst,
                                 const int* __restrict__ flag, int n) {
    int i = blockIdx.x * 256 + threadIdx.x;
    if (i >= n) return;
    if (flag[0]) ((unsigned short*)dst)[i] = f2bf(src[i]);
    else         ((float*)dst)[i] = src[i];
}

// ---- block reductions (blockDim.x == 256) ----
__device__ __forceinline__ float blk_sum256(float v, float* red) {
    #pragma unroll
    for (int off = 32; off; off >>= 1) v += __shfl_down(v, off, 64);
    int tid = threadIdx.x;
    __syncthreads();
    if ((tid & 63) == 0) red[tid >> 6] = v;
    __syncthreads();
    return red[0] + red[1] + red[2] + red[3];
}
__device__ __forceinline__ float blk_max256(float v, float* red) {
    #pragma unroll
    for (int off = 32; off; off >>= 1) v = fmaxf(v, __shfl_down(v, off, 64));
    int tid = threadIdx.x;
    __syncthreads();
    if ((tid & 63) == 0) red[tid >> 6] = v;
    __syncthreads();
    return fmaxf(fmaxf(red[0], red[1]), fmaxf(red[2], red[3]));
}

// ---- AdaLN: h = (exp(loggamma)*[2*(1-0.1*hn)*hn] + beta) * m ----
__global__ __launch_bounds__(256)
void adaln_kernel(const float* __restrict__ x,
                  const float* __restrict__ emb,    // (N_LEVELS, 2*D) fp32, this layer
                  const int* __restrict__ lvl,
                  const float* __restrict__ mvec,   // (B*T) fp32
                  unsigned short* __restrict__ h) { // bf16 out
    __shared__ float red[4];
    int row = blockIdx.x;
    int b = row / TT;
    int tid = threadIdx.x;
    const float* xr = x + (size_t)row * D_MODEL;

    float s = 0.f;
    for (int j = tid; j < D_MODEL; j += 256) s += xr[j];
    float mu = blk_sum256(s, red) * (1.0f / D_MODEL);

    float vs = 0.f;
    for (int j = tid; j < D_MODEL; j += 256) { float d = xr[j] - mu; vs += d * d; }
    float var = blk_sum256(vs, red) * (1.0f / D_MODEL);
    float rstd = rsqrtf(var + EPSV);

    int lv = lvl[b];
    const float* g = emb + (size_t)lv * (2 * D_MODEL);
    float mval = mvec[row];
    unsigned short* hr = h + (size_t)row * D_MODEL;
    for (int j = tid; j < D_MODEL; j += 256) {
        float hn = (xr[j] - mu) * rstd;
        float h2 = 2.0f * (1.0f - 0.1f * hn) * hn;
        float o = __expf(g[j]) * h2 + g[D_MODEL + j];
        hr[j] = f2bf(o * mval);
    }
}

// ---- MFMA GEMM: C(MxN) = A(MxK,bf16) @ B(KxN,bf16) + fused epilogues ----
#define BM 64
#define BN 64
#define BK 32
#define BKP 40

#define EPI_STORE 0
#define EPI_GELU  1
#define EPI_RESID 2

__global__ __launch_bounds__(256)
void gemm_kernel(const unsigned short* __restrict__ A,
                 const unsigned short* __restrict__ Bw,
                 const float* __restrict__ bias,     // fp32 (N) or nullptr
                 unsigned short* __restrict__ outb,  // bf16 out (STORE/GELU)
                 const float* __restrict__ xin,      // fp32 residual in (RESID)
                 float* __restrict__ xout,           // fp32 out (RESID): (xin+v)*m
                 const float* __restrict__ mvec,     // fp32 mask (M) (RESID)
                 int M, int N, int K, int mode) {
    __shared__ __align__(16) unsigned short As[BM * BKP];
    __shared__ __align__(16) unsigned short Bs[BN * BKP];   // transposed [n][k]
    int tid = threadIdx.x;
    int tileN = blockIdx.x * BN;
    int tileM = blockIdx.y * BM;
    int lane = tid & 63;
    int wave = tid >> 6;
    int wm = (wave & 1) * 32;
    int wn = (wave >> 1) * 32;
    int quad = lane >> 4;
    int l16 = lane & 15;

    f32x4 acc[2][2] = {};

    int ar = tid >> 2;            // 0..63
    int ac = (tid & 3) * 8;       // 0,8,16,24
    int bk = tid >> 3;            // 0..31
    int bn = (tid & 7) * 8;       // 0..56

    const unsigned short* Aptr = A + (size_t)(tileM + ar) * K + ac;
    const unsigned short* Bptr = Bw + (size_t)bk * N + tileN + bn;

    for (int k0 = 0; k0 < K; k0 += BK) {
        uint4 av = *(const uint4*)(Aptr + k0);
        *(uint4*)(&As[ar * BKP + ac]) = av;

        uint4 bv = *(const uint4*)(Bptr + (size_t)k0 * N);
        unsigned short tmp[8];
        *(uint4*)tmp = bv;
        #pragma unroll
        for (int jj = 0; jj < 8; ++jj) Bs[(bn + jj) * BKP + bk] = tmp[jj];
        __syncthreads();

        bf16x8 af[2], bfr[2];
        #pragma unroll
        for (int mi = 0; mi < 2; ++mi)
            af[mi] = *(const bf16x8*)(&As[(wm + mi * 16 + l16) * BKP + quad * 8]);
        #pragma unroll
        for (int ni = 0; ni < 2; ++ni)
            bfr[ni] = *(const bf16x8*)(&Bs[(wn + ni * 16 + l16) * BKP + quad * 8]);
        #pragma unroll
        for (int mi = 0; mi < 2; ++mi)
            #pragma unroll
            for (int ni = 0; ni < 2; ++ni)
                acc[mi][ni] = __builtin_amdgcn_mfma_f32_16x16x32_bf16(af[mi], bfr[ni], acc[mi][ni], 0, 0, 0);
        __syncthreads();
    }

    #pragma unroll
    for (int mi = 0; mi < 2; ++mi)
    for (int ni = 0; ni < 2; ++ni) {
        #pragma unroll
        for (int r = 0; r < 4; ++r) {
            int row = tileM + wm + mi * 16 + quad * 4 + r;
            int col = tileN + wn + ni * 16 + l16;
            float v = acc[mi][ni][r];
            if (bias) v += bias[col];
            size_t idx = (size_t)row * N + col;
            if (mode == EPI_STORE) {
                outb[idx] = f2bf(v);
            } else if (mode == EPI_GELU) {
                float gel = 0.5f * v * (1.0f + erff(v * 0.70710678118654752f));
                outb[idx] = f2bf(gel);
            } else {
                float mval = mvec[row];
                xout[idx] = (xin[idx] + v) * mval;
            }
        }
    }
}

// ---- attention: one block per (b, head, query-row); two-pass softmax ----
__global__ __launch_bounds__(256)
void attn_kernel(const unsigned short* __restrict__ qkv,  // (B*T) x 3072 : [q|k|v]
                 unsigned short* __restrict__ o) {        // (B*T) x 1024
    __shared__ float qs[DH];
    __shared__ float sc[TT];
    __shared__ float red[4];
    __shared__ float pv[4 * DH];
    int qi = blockIdx.x;
    int hd = blockIdx.y;
    int b  = blockIdx.z;
    int tid = threadIdx.x;
    const unsigned short* base = qkv + (size_t)b * TT * 3072;

    if (tid < DH) qs[tid] = bf2f(base[(size_t)qi * 3072 + hd * DH + tid]);
    __syncthreads();

    for (int j = tid; j <= qi; j += 256) {
        const unsigned short* kr = base + (size_t)j * 3072 + 1024 + hd * DH;
        float dot = 0.f;
        #pragma unroll
        for (int d = 0; d < DH; ++d) dot += qs[d] * bf2f(kr[d]);
        sc[j] = dot * 0.125f;
    }
    __syncthreads();

    float lm = -3.4e38f;
    for (int j = tid; j <= qi; j += 256) lm = fmaxf(lm, sc[j]);
    float mx = blk_max256(lm, red);

    float ls = 0.f;
    for (int j = tid; j <= qi; j += 256) { float e = __expf(sc[j] - mx); sc[j] = e; ls += e; }
    __syncthreads();
    float sum = blk_sum256(ls, red);
    float inv = 1.0f / sum;

    int d = tid & 63, part = tid >> 6;
    float a = 0.f;
    for (int j = part; j <= qi; j += 4)
        a += sc[j] * bf2f(base[(size_t)j * 3072 + 2048 + hd * DH + d]);
    pv[part * DH + d] = a;
    __syncthreads();
    if (tid < DH) {
        float r = (pv[tid] + pv[DH + tid] + pv[2 * DH + tid] + pv[3 * DH + tid]) * inv;
        o[(size_t)(b * TT + qi) * D_MODEL + hd * DH + tid] = f2bf(r);
    }
}

// ---- workspace layout (bytes) ----
#define MB (1048576u)
#define WS_FLAG   0u
#define WS_MF     4096u                    // 2048 fp32
#define WS_EMBA   (WS_MF + 8192u)          // 65536 fp32
#define WS_EMBF   (WS_EMBA + 262144u)
#define WS_BOUT   (WS_EMBF + 262144u)      // 4096 fp32
#define WS_B1     (WS_BOUT + 16384u)       // 16384 fp32
#define WS_B2     (WS_B1 + 65536u)         // 4096 fp32
#define WS_XF     (1u*MB)                  // 8 MB fp32
#define WS_H      (9u*MB)                  // 4 MB bf16
#define WS_QKV    (13u*MB)                 // 12 MB bf16
#define WS_OB     (25u*MB)                 // 4 MB bf16
#define WS_FF1    (29u*MB)                 // 16 MB bf16
#define WS_WQKV   (45u*MB)                 // 6 MB bf16 (per-layer)
#define WS_WOUT   (51u*MB)                 // 2 MB
#define WS_W1     (53u*MB)                 // 8 MB
#define WS_W2     (61u*MB)                 // 8 MB  (end: 69 MB)

extern "C" void kernel_launch(void* const* d_in, const int* in_sizes, int n_in,
                              void* d_out, int out_size, void* d_ws, size_t ws_size,
                              hipStream_t stream) {
    const void* x_in  = d_in[0];
    const void* m_in  = d_in[1];
    const int*  l_in  = (const int*)d_in[2];
    const void* Wqkv  = d_in[3];
    const void* Wout  = d_in[4];
    const void* boutp = d_in[5];
    const void* ada_a = d_in[6];
    const void* ada_f = d_in[7];
    const void* W1    = d_in[8];
    const void* b1    = d_in[9];
    const void* W2    = d_in[10];
    const void* b2    = d_in[11];

    char* ws = (char*)d_ws;
    int*            flag = (int*)(ws + WS_FLAG);
    float*          mf   = (float*)(ws + WS_MF);
    float*          embA = (float*)(ws + WS_EMBA);
    float*          embF = (float*)(ws + WS_EMBF);
    float*          boutf= (float*)(ws + WS_BOUT);
    float*          b1f  = (float*)(ws + WS_B1);
    float*          b2f  = (float*)(ws + WS_B2);
    float*          xf   = (float*)(ws + WS_XF);
    unsigned short* h    = (unsigned short*)(ws + WS_H);
    unsigned short* qkv  = (unsigned short*)(ws + WS_QKV);
    unsigned short* ob   = (unsigned short*)(ws + WS_OB);
    unsigned short* ff1  = (unsigned short*)(ws + WS_FF1);
    unsigned short* wqkvb= (unsigned short*)(ws + WS_WQKV);
    unsigned short* woutb= (unsigned short*)(ws + WS_WOUT);
    unsigned short* w1b  = (unsigned short*)(ws + WS_W1);
    unsigned short* w2b  = (unsigned short*)(ws + WS_W2);

    const int n = MM * D_MODEL;  // 2,097,152

    detect_kernel<<<1, 256, 0, stream>>>((const unsigned short*)x_in, flag);

    load_f32_kernel<<<n / 256, 256, 0, stream>>>(x_in, xf, flag, n);
    load_f32_kernel<<<MM / 256, 256, 0, stream>>>(m_in, mf, flag, MM);
    load_f32_kernel<<<65536 / 256, 256, 0, stream>>>(ada_a, embA, flag, 65536);
    load_f32_kernel<<<65536 / 256, 256, 0, stream>>>(ada_f, embF, flag, 65536);
    load_f32_kernel<<<4096 / 256, 256, 0, stream>>>(boutp, boutf, flag, 4096);
    load_f32_kernel<<<16384 / 256, 256, 0, stream>>>(b1, b1f, flag, 16384);
    load_f32_kernel<<<4096 / 256, 256, 0, stream>>>(b2, b2f, flag, 4096);

    const int nqkv = D_MODEL * 3 * D_MODEL;   // 3,145,728
    const int nsq  = D_MODEL * D_MODEL;       // 1,048,576
    const int nw1  = D_MODEL * 4 * D_MODEL;   // 4,194,304

    for (int i = 0; i < N_LAYERS; ++i) {
        load_bf16_off_kernel<<<nqkv / 256, 256, 0, stream>>>(Wqkv, wqkvb, flag, nqkv, (long long)i * nqkv);
        load_bf16_off_kernel<<<nsq  / 256, 256, 0, stream>>>(Wout, woutb, flag, nsq,  (long long)i * nsq);
        load_bf16_off_kernel<<<nw1  / 256, 256, 0, stream>>>(W1,   w1b,   flag, nw1,  (long long)i * nw1);
        load_bf16_off_kernel<<<nw1  / 256, 256, 0, stream>>>(W2,   w2b,   flag, nw1,  (long long)i * nw1);

        // ---- attention sub-block ----
        adaln_kernel<<<MM, 256, 0, stream>>>(xf, embA + (size_t)i * N_LEVELS * 2 * D_MODEL, l_in, mf, h);
        gemm_kernel<<<dim3(3072 / BN, MM / BM), 256, 0, stream>>>(
            h, wqkvb, nullptr, qkv, nullptr, nullptr, nullptr, MM, 3072, D_MODEL, EPI_STORE);
        attn_kernel<<<dim3(TT, N_HEADS, BB), 256, 0, stream>>>(qkv, ob);
        gemm_kernel<<<dim3(D_MODEL / BN, MM / BM), 256, 0, stream>>>(
            ob, woutb, boutf + (size_t)i * D_MODEL, nullptr, xf, xf, mf, MM, D_MODEL, D_MODEL, EPI_RESID);
        // ---- FFN sub-block ----
        adaln_kernel<<<MM, 256, 0, stream>>>(xf, embF + (size_t)i * N_LEVELS * 2 * D_MODEL, l_in, mf, h);
        gemm_kernel<<<dim3(4096 / BN, MM / BM), 256, 0, stream>>>(
            h, w1b, b1f + (size_t)i * 4 * D_MODEL, ff1, nullptr, nullptr, nullptr, MM, 4096, D_MODEL, EPI_GELU);
        gemm_kernel<<<dim3(D_MODEL / BN, MM / BM), 256, 0, stream>>>(
            ff1, w2b, b2f + (size_t)i * D_MODEL, nullptr, xf, xf, mf, MM, D_MODEL, 4096, EPI_RESID);
    }

    store_out_kernel<<<n / 256, 256, 0, stream>>>(xf, d_out, flag, n);
}

// Round 3
// 1772.079 us; speedup vs baseline: 3.8725x; 3.8725x over previous
//
#include <hip/hip_runtime.h>

#define D_MODEL 1024
#define N_HEADS 16
#define DH 64
#define N_LAYERS 4
#define N_LEVELS 8
#define BB 2
#define TT 1024
#define MM (BB*TT)
#define EPSV 1e-5f

typedef float f32x4 __attribute__((ext_vector_type(4)));
typedef short bf16x8 __attribute__((ext_vector_type(8)));

__device__ __forceinline__ float bf2f(unsigned short u) {
    union { unsigned int i; float f; } c; c.i = ((unsigned int)u) << 16; return c.f;
}
__device__ __forceinline__ unsigned short f2bf(float f) {
    union { float f; unsigned int i; } c; c.f = f;
    unsigned int x = c.i;
    return (unsigned short)((x + 0x7fffu + ((x >> 16) & 1u)) >> 16);  // RNE
}

// ---- dtype detection: even u16 halves of an fp32 stream are uniform mantissa
// bits (~12% land in bf16-exponent band); of a bf16 stream ~100% structured.
__global__ void detect_kernel(const unsigned short* __restrict__ x, int* __restrict__ flag) {
    __shared__ int cnts[256];
    int cnt = 0;
    for (int i = threadIdx.x; i < 16384; i += 256) {
        unsigned short u = x[2 * i];
        int e = (u >> 7) & 0xFF;
        if (e >= 110 && e <= 140) cnt++;
    }
    cnts[threadIdx.x] = cnt;
    __syncthreads();
    for (int s = 128; s; s >>= 1) {
        if (threadIdx.x < s) cnts[threadIdx.x] += cnts[threadIdx.x + s];
        __syncthreads();
    }
    if (threadIdx.x == 0) flag[0] = (cnts[0] > 12000) ? 1 : 0;  // 1 = inputs are bf16
}

// ---- converters ----
__global__ void load_f32_kernel(const void* __restrict__ src, float* __restrict__ dst,
                                const int* __restrict__ flag, int n) {
    int i = blockIdx.x * 256 + threadIdx.x;
    if (i >= n) return;
    dst[i] = flag[0] ? bf2f(((const unsigned short*)src)[i]) : ((const float*)src)[i];
}
__global__ void load_bf16_off_kernel(const void* __restrict__ src, unsigned short* __restrict__ dst,
                                     const int* __restrict__ flag, int n, long long off) {
    int i = blockIdx.x * 256 + threadIdx.x;
    if (i >= n) return;
    long long j = off + i;
    dst[i] = flag[0] ? ((const unsigned short*)src)[j] : f2bf(((const float*)src)[j]);
}
__global__ void store_out_kernel(const float* __restrict__ src, void* __restrict__ dst,
                                 const int* __restrict__ flag, int n) {
    int i = blockIdx.x * 256 + threadIdx.x;
    if (i >= n) return;
    if (flag[0]) ((unsigned short*)dst)[i] = f2bf(src[i]);
    else         ((float*)dst)[i] = src[i];
}

// ---- block reductions (blockDim.x == 256) ----
__device__ __forceinline__ float blk_sum256(float v, float* red) {
    #pragma unroll
    for (int off = 32; off; off >>= 1) v += __shfl_down(v, off, 64);
    int tid = threadIdx.x;
    __syncthreads();
    if ((tid & 63) == 0) red[tid >> 6] = v;
    __syncthreads();
    return red[0] + red[1] + red[2] + red[3];
}

// ---- AdaLN: h = (exp(loggamma)*[2*(1-0.1*hn)*hn] + beta) * m ----
__global__ __launch_bounds__(256)
void adaln_kernel(const float* __restrict__ x,
                  const float* __restrict__ emb,    // (N_LEVELS, 2*D) fp32, this layer
                  const int* __restrict__ lvl,
                  const float* __restrict__ mvec,   // (B*T) fp32
                  unsigned short* __restrict__ h) { // bf16 out
    __shared__ float red[4];
    int row = blockIdx.x;
    int b = row / TT;
    int tid = threadIdx.x;
    const float* xr = x + (size_t)row * D_MODEL;

    float s = 0.f;
    for (int j = tid; j < D_MODEL; j += 256) s += xr[j];
    float mu = blk_sum256(s, red) * (1.0f / D_MODEL);

    float vs = 0.f;
    for (int j = tid; j < D_MODEL; j += 256) { float d = xr[j] - mu; vs += d * d; }
    float var = blk_sum256(vs, red) * (1.0f / D_MODEL);
    float rstd = rsqrtf(var + EPSV);

    int lv = lvl[b];
    const float* g = emb + (size_t)lv * (2 * D_MODEL);
    float mval = mvec[row];
    unsigned short* hr = h + (size_t)row * D_MODEL;
    for (int j = tid; j < D_MODEL; j += 256) {
        float hn = (xr[j] - mu) * rstd;
        float h2 = 2.0f * (1.0f - 0.1f * hn) * hn;
        float o = __expf(g[j]) * h2 + g[D_MODEL + j];
        hr[j] = f2bf(o * mval);
    }
}

// ---- MFMA GEMM: C(MxN) = A(MxK,bf16) @ B(KxN,bf16) + fused epilogues ----
#define BM 64
#define BN 64
#define BK 32
#define BKP 40

#define EPI_STORE 0
#define EPI_GELU  1
#define EPI_RESID 2

__global__ __launch_bounds__(256)
void gemm_kernel(const unsigned short* __restrict__ A,
                 const unsigned short* __restrict__ Bw,
                 const float* __restrict__ bias,     // fp32 (N) or nullptr
                 unsigned short* __restrict__ outb,  // bf16 out (STORE/GELU)
                 const float* __restrict__ xin,      // fp32 residual in (RESID)
                 float* __restrict__ xout,           // fp32 out (RESID): (xin+v)*m
                 const float* __restrict__ mvec,     // fp32 mask (M) (RESID)
                 int M, int N, int K, int mode) {
    __shared__ __align__(16) unsigned short As[BM * BKP];
    __shared__ __align__(16) unsigned short Bs[BN * BKP];   // transposed [n][k]
    int tid = threadIdx.x;
    int tileN = blockIdx.x * BN;
    int tileM = blockIdx.y * BM;
    int lane = tid & 63;
    int wave = tid >> 6;
    int wm = (wave & 1) * 32;
    int wn = (wave >> 1) * 32;
    int quad = lane >> 4;
    int l16 = lane & 15;

    f32x4 acc[2][2] = {};

    int ar = tid >> 2;            // 0..63
    int ac = (tid & 3) * 8;       // 0,8,16,24
    int bk = tid >> 3;            // 0..31
    int bn = (tid & 7) * 8;       // 0..56

    const unsigned short* Aptr = A + (size_t)(tileM + ar) * K + ac;
    const unsigned short* Bptr = Bw + (size_t)bk * N + tileN + bn;

    for (int k0 = 0; k0 < K; k0 += BK) {
        uint4 av = *(const uint4*)(Aptr + k0);
        *(uint4*)(&As[ar * BKP + ac]) = av;

        uint4 bv = *(const uint4*)(Bptr + (size_t)k0 * N);
        unsigned short tmp[8];
        *(uint4*)tmp = bv;
        #pragma unroll
        for (int jj = 0; jj < 8; ++jj) Bs[(bn + jj) * BKP + bk] = tmp[jj];
        __syncthreads();

        bf16x8 af[2], bfr[2];
        #pragma unroll
        for (int mi = 0; mi < 2; ++mi)
            af[mi] = *(const bf16x8*)(&As[(wm + mi * 16 + l16) * BKP + quad * 8]);
        #pragma unroll
        for (int ni = 0; ni < 2; ++ni)
            bfr[ni] = *(const bf16x8*)(&Bs[(wn + ni * 16 + l16) * BKP + quad * 8]);
        #pragma unroll
        for (int mi = 0; mi < 2; ++mi)
            #pragma unroll
            for (int ni = 0; ni < 2; ++ni)
                acc[mi][ni] = __builtin_amdgcn_mfma_f32_16x16x32_bf16(af[mi], bfr[ni], acc[mi][ni], 0, 0, 0);
        __syncthreads();
    }

    #pragma unroll
    for (int mi = 0; mi < 2; ++mi)
    for (int ni = 0; ni < 2; ++ni) {
        #pragma unroll
        for (int r = 0; r < 4; ++r) {
            int row = tileM + wm + mi * 16 + quad * 4 + r;
            int col = tileN + wn + ni * 16 + l16;
            float v = acc[mi][ni][r];
            if (bias) v += bias[col];
            size_t idx = (size_t)row * N + col;
            if (mode == EPI_STORE) {
                outb[idx] = f2bf(v);
            } else if (mode == EPI_GELU) {
                float gel = 0.5f * v * (1.0f + erff(v * 0.70710678118654752f));
                outb[idx] = f2bf(gel);
            } else {
                float mval = mvec[row];
                xout[idx] = (xin[idx] + v) * mval;
            }
        }
    }
}

// ---- flash attention: one block per (q-tile 64, head, batch); MFMA QK^T and PV,
// online softmax. Padding subsumed: pad rows of h are zero + epilogue re-masks.
#define FA_DPAD 72   // 144 B stride, 16B-aligned for ds_read_b128

__global__ __launch_bounds__(256)
void fattn_kernel(const unsigned short* __restrict__ qkv,  // (B*T) x 3072 [q|k|v]
                  unsigned short* __restrict__ o) {        // (B*T) x 1024
    __shared__ __align__(16) unsigned short Qs[64 * FA_DPAD];
    __shared__ __align__(16) unsigned short Ks[64 * FA_DPAD];
    __shared__ __align__(16) unsigned short Vs[64 * FA_DPAD];  // transposed [dh][j]
    __shared__ __align__(16) unsigned short Ps[64 * FA_DPAD];

    int qt  = blockIdx.x;      // 0..15
    int hd  = blockIdx.y;
    int b   = blockIdx.z;
    int tid = threadIdx.x;
    int wave = tid >> 6;
    int lane = tid & 63;
    int quad = lane >> 4;
    int l16  = lane & 15;

    const unsigned short* base = qkv + (size_t)b * TT * 3072;

    // stage Q tile (rows qt*64..+63): coalesced, row = tid>>2, 2x16B per thread
    {
        int r = tid >> 2, c = (tid & 3) * 16;
        const unsigned short* src = base + (size_t)(qt * 64 + r) * 3072 + hd * DH + c;
        *(uint4*)(&Qs[r * FA_DPAD + c])     = *(const uint4*)(src);
        *(uint4*)(&Qs[r * FA_DPAD + c + 8]) = *(const uint4*)(src + 8);
    }
    __syncthreads();

    // Q fragments are loop-invariant
    bf16x8 aq[2];
    #pragma unroll
    for (int cc = 0; cc < 2; ++cc)
        aq[cc] = *(const bf16x8*)(&Qs[(wave * 16 + l16) * FA_DPAD + cc * 32 + quad * 8]);

    f32x4 Oacc[4] = {};            // 16 rows x 64 dh per wave
    float mstate[4], lstate[4];
    #pragma unroll
    for (int r = 0; r < 4; ++r) { mstate[r] = -1e30f; lstate[r] = 0.f; }

    for (int jt = 0; jt <= qt; ++jt) {
        __syncthreads();   // previous iteration's Ks/Vs readers done
        {   // K tile, coalesced
            int r = tid >> 2, c = (tid & 3) * 16;
            const unsigned short* src = base + (size_t)(jt * 64 + r) * 3072 + 1024 + hd * DH + c;
            *(uint4*)(&Ks[r * FA_DPAD + c])     = *(const uint4*)(src);
            *(uint4*)(&Ks[r * FA_DPAD + c + 8]) = *(const uint4*)(src + 8);
        }
        {   // V tile, transposed into Vs[dh][j]; lane=j → conflict-free stores
            int j = lane, c = wave * 16;
            const unsigned short* src = base + (size_t)(jt * 64 + j) * 3072 + 2048 + hd * DH + c;
            unsigned short tmp[16];
            *(uint4*)(tmp)     = *(const uint4*)(src);
            *(uint4*)(tmp + 8) = *(const uint4*)(src + 8);
            #pragma unroll
            for (int d = 0; d < 16; ++d) Vs[(c + d) * FA_DPAD + j] = tmp[d];
        }
        __syncthreads();

        // S = Q K^T (wave's 16 rows x 64 cols)
        f32x4 S[4] = {};
        #pragma unroll
        for (int t = 0; t < 4; ++t)
            #pragma unroll
            for (int cc = 0; cc < 2; ++cc) {
                bf16x8 bk = *(const bf16x8*)(&Ks[(t * 16 + l16) * FA_DPAD + cc * 32 + quad * 8]);
                S[t] = __builtin_amdgcn_mfma_f32_16x16x32_bf16(aq[cc], bk, S[t], 0, 0, 0);
            }

        int qrow0 = qt * 64 + wave * 16 + quad * 4;
        bool diag = (jt == qt);
        float mnew[4];
        #pragma unroll
        for (int r = 0; r < 4; ++r) {
            float v = -1e30f;
            #pragma unroll
            for (int t = 0; t < 4; ++t) {
                float s = S[t][r] * 0.125f;
                if (diag) {
                    int j = jt * 64 + t * 16 + l16;
                    if (j > qrow0 + r) s = -1e30f;
                }
                S[t][r] = s;
                v = fmaxf(v, s);
            }
            v = fmaxf(v, __shfl_xor(v, 1, 64));
            v = fmaxf(v, __shfl_xor(v, 2, 64));
            v = fmaxf(v, __shfl_xor(v, 4, 64));
            v = fmaxf(v, __shfl_xor(v, 8, 64));
            mnew[r] = fmaxf(mstate[r], v);
        }

        #pragma unroll
        for (int r = 0; r < 4; ++r) {
            float rs = 0.f;
            #pragma unroll
            for (int t = 0; t < 4; ++t) {
                float p = __expf(S[t][r] - mnew[r]);
                rs += p;
                Ps[(wave * 16 + quad * 4 + r) * FA_DPAD + t * 16 + l16] = f2bf(p);
            }
            rs += __shfl_xor(rs, 1, 64);
            rs += __shfl_xor(rs, 2, 64);
            rs += __shfl_xor(rs, 4, 64);
            rs += __shfl_xor(rs, 8, 64);
            float alpha = __expf(mstate[r] - mnew[r]);
            lstate[r] = alpha * lstate[r] + rs;
            mstate[r] = mnew[r];
            #pragma unroll
            for (int t = 0; t < 4; ++t) Oacc[t][r] *= alpha;
        }

        // PV: P strip written & read by the SAME wave (in-order LDS per wave)
        #pragma unroll
        for (int cc = 0; cc < 2; ++cc) {
            bf16x8 ap = *(const bf16x8*)(&Ps[(wave * 16 + l16) * FA_DPAD + cc * 32 + quad * 8]);
            #pragma unroll
            for (int t = 0; t < 4; ++t) {
                bf16x8 bv = *(const bf16x8*)(&Vs[(t * 16 + l16) * FA_DPAD + cc * 32 + quad * 8]);
                Oacc[t] = __builtin_amdgcn_mfma_f32_16x16x32_bf16(ap, bv, Oacc[t], 0, 0, 0);
            }
        }
    }

    #pragma unroll
    for (int r = 0; r < 4; ++r) {
        float inv = 1.0f / lstate[r];
        int qi = qt * 64 + wave * 16 + quad * 4 + r;
        unsigned short* orow = o + (size_t)(b * TT + qi) * D_MODEL + hd * DH;
        #pragma unroll
        for (int t = 0; t < 4; ++t)
            orow[t * 16 + l16] = f2bf(Oacc[t][r] * inv);
    }
}

// ---- workspace layout (bytes) ----
#define MB (1048576u)
#define WS_FLAG   0u
#define WS_MF     4096u                    // 2048 fp32
#define WS_EMBA   (WS_MF + 8192u)          // 65536 fp32
#define WS_EMBF   (WS_EMBA + 262144u)
#define WS_BOUT   (WS_EMBF + 262144u)      // 4096 fp32
#define WS_B1     (WS_BOUT + 16384u)       // 16384 fp32
#define WS_B2     (WS_B1 + 65536u)         // 4096 fp32
#define WS_XF     (1u*MB)                  // 8 MB fp32
#define WS_H      (9u*MB)                  // 4 MB bf16
#define WS_QKV    (13u*MB)                 // 12 MB bf16
#define WS_OB     (25u*MB)                 // 4 MB bf16
#define WS_FF1    (29u*MB)                 // 16 MB bf16
#define WS_WQKV   (45u*MB)                 // 6 MB bf16 (per-layer)
#define WS_WOUT   (51u*MB)                 // 2 MB
#define WS_W1     (53u*MB)                 // 8 MB
#define WS_W2     (61u*MB)                 // 8 MB  (end: 69 MB)

extern "C" void kernel_launch(void* const* d_in, const int* in_sizes, int n_in,
                              void* d_out, int out_size, void* d_ws, size_t ws_size,
                              hipStream_t stream) {
    const void* x_in  = d_in[0];
    const void* m_in  = d_in[1];
    const int*  l_in  = (const int*)d_in[2];
    const void* Wqkv  = d_in[3];
    const void* Wout  = d_in[4];
    const void* boutp = d_in[5];
    const void* ada_a = d_in[6];
    const void* ada_f = d_in[7];
    const void* W1    = d_in[8];
    const void* b1    = d_in[9];
    const void* W2    = d_in[10];
    const void* b2    = d_in[11];

    char* ws = (char*)d_ws;
    int*            flag = (int*)(ws + WS_FLAG);
    float*          mf   = (float*)(ws + WS_MF);
    float*          embA = (float*)(ws + WS_EMBA);
    float*          embF = (float*)(ws + WS_EMBF);
    float*          boutf= (float*)(ws + WS_BOUT);
    float*          b1f  = (float*)(ws + WS_B1);
    float*          b2f  = (float*)(ws + WS_B2);
    float*          xf   = (float*)(ws + WS_XF);
    unsigned short* h    = (unsigned short*)(ws + WS_H);
    unsigned short* qkv  = (unsigned short*)(ws + WS_QKV);
    unsigned short* ob   = (unsigned short*)(ws + WS_OB);
    unsigned short* ff1  = (unsigned short*)(ws + WS_FF1);
    unsigned short* wqkvb= (unsigned short*)(ws + WS_WQKV);
    unsigned short* woutb= (unsigned short*)(ws + WS_WOUT);
    unsigned short* w1b  = (unsigned short*)(ws + WS_W1);
    unsigned short* w2b  = (unsigned short*)(ws + WS_W2);

    const int n = MM * D_MODEL;  // 2,097,152

    detect_kernel<<<1, 256, 0, stream>>>((const unsigned short*)x_in, flag);

    load_f32_kernel<<<n / 256, 256, 0, stream>>>(x_in, xf, flag, n);
    load_f32_kernel<<<MM / 256, 256, 0, stream>>>(m_in, mf, flag, MM);
    load_f32_kernel<<<65536 / 256, 256, 0, stream>>>(ada_a, embA, flag, 65536);
    load_f32_kernel<<<65536 / 256, 256, 0, stream>>>(ada_f, embF, flag, 65536);
    load_f32_kernel<<<4096 / 256, 256, 0, stream>>>(boutp, boutf, flag, 4096);
    load_f32_kernel<<<16384 / 256, 256, 0, stream>>>(b1, b1f, flag, 16384);
    load_f32_kernel<<<4096 / 256, 256, 0, stream>>>(b2, b2f, flag, 4096);

    const int nqkv = D_MODEL * 3 * D_MODEL;   // 3,145,728
    const int nsq  = D_MODEL * D_MODEL;       // 1,048,576
    const int nw1  = D_MODEL * 4 * D_MODEL;   // 4,194,304

    for (int i = 0; i < N_LAYERS; ++i) {
        load_bf16_off_kernel<<<nqkv / 256, 256, 0, stream>>>(Wqkv, wqkvb, flag, nqkv, (long long)i * nqkv);
        load_bf16_off_kernel<<<nsq  / 256, 256, 0, stream>>>(Wout, woutb, flag, nsq,  (long long)i * nsq);
        load_bf16_off_kernel<<<nw1  / 256, 256, 0, stream>>>(W1,   w1b,   flag, nw1,  (long long)i * nw1);
        load_bf16_off_kernel<<<nw1  / 256, 256, 0, stream>>>(W2,   w2b,   flag, nw1,  (long long)i * nw1);

        // ---- attention sub-block ----
        adaln_kernel<<<MM, 256, 0, stream>>>(xf, embA + (size_t)i * N_LEVELS * 2 * D_MODEL, l_in, mf, h);
        gemm_kernel<<<dim3(3072 / BN, MM / BM), 256, 0, stream>>>(
            h, wqkvb, nullptr, qkv, nullptr, nullptr, nullptr, MM, 3072, D_MODEL, EPI_STORE);
        fattn_kernel<<<dim3(TT / 64, N_HEADS, BB), 256, 0, stream>>>(qkv, ob);
        gemm_kernel<<<dim3(D_MODEL / BN, MM / BM), 256, 0, stream>>>(
            ob, woutb, boutf + (size_t)i * D_MODEL, nullptr, xf, xf, mf, MM, D_MODEL, D_MODEL, EPI_RESID);
        // ---- FFN sub-block ----
        adaln_kernel<<<MM, 256, 0, stream>>>(xf, embF + (size_t)i * N_LEVELS * 2 * D_MODEL, l_in, mf, h);
        gemm_kernel<<<dim3(4096 / BN, MM / BM), 256, 0, stream>>>(
            h, w1b, b1f + (size_t)i * 4 * D_MODEL, ff1, nullptr, nullptr, nullptr, MM, 4096, D_MODEL, EPI_GELU);
        gemm_kernel<<<dim3(D_MODEL / BN, MM / BM), 256, 0, stream>>>(
            ff1, w2b, b2f + (size_t)i * D_MODEL, nullptr, xf, xf, mf, MM, D_MODEL, 4096, EPI_RESID);
    }

    store_out_kernel<<<n / 256, 256, 0, stream>>>(xf, d_out, flag, n);
}

// Round 4
// 1338.913 us; speedup vs baseline: 5.1254x; 1.3235x over previous
//
#include <hip/hip_runtime.h>

#define D_MODEL 1024
#define N_HEADS 16
#define DH 64
#define N_LAYERS 4
#define N_LEVELS 8
#define BB 2
#define TT 1024
#define MM (BB*TT)
#define EPSV 1e-5f

typedef float f32x4 __attribute__((ext_vector_type(4)));
typedef short bf16x8 __attribute__((ext_vector_type(8)));

__device__ __forceinline__ float bf2f(unsigned short u) {
    union { unsigned int i; float f; } c; c.i = ((unsigned int)u) << 16; return c.f;
}
__device__ __forceinline__ unsigned short f2bf(float f) {
    union { float f; unsigned int i; } c; c.f = f;
    unsigned int x = c.i;
    return (unsigned short)((x + 0x7fffu + ((x >> 16) & 1u)) >> 16);  // RNE
}

// async global->LDS, 16 B per lane; LDS dest = base + lane*16 (wave-uniform base)
__device__ __forceinline__ void gl_lds16(const unsigned short* g, unsigned short* l) {
    __builtin_amdgcn_global_load_lds(
        (const __attribute__((address_space(1))) unsigned int*)g,
        (__attribute__((address_space(3))) unsigned int*)l,
        16, 0, 0);
}

// ---- dtype detection (fp32 vs bf16 input buffers) ----
__global__ void detect_kernel(const unsigned short* __restrict__ x, int* __restrict__ flag) {
    __shared__ int cnts[256];
    int cnt = 0;
    for (int i = threadIdx.x; i < 16384; i += 256) {
        unsigned short u = x[2 * i];
        int e = (u >> 7) & 0xFF;
        if (e >= 110 && e <= 140) cnt++;
    }
    cnts[threadIdx.x] = cnt;
    __syncthreads();
    for (int s = 128; s; s >>= 1) {
        if (threadIdx.x < s) cnts[threadIdx.x] += cnts[threadIdx.x + s];
        __syncthreads();
    }
    if (threadIdx.x == 0) flag[0] = (cnts[0] > 12000) ? 1 : 0;  // 1 = inputs are bf16
}

// ---- converters ----
__global__ void load_f32_kernel(const void* __restrict__ src, float* __restrict__ dst,
                                const int* __restrict__ flag, int n) {
    int i = blockIdx.x * 256 + threadIdx.x;
    if (i >= n) return;
    dst[i] = flag[0] ? bf2f(((const unsigned short*)src)[i]) : ((const float*)src)[i];
}
__global__ void store_out_kernel(const float* __restrict__ src, void* __restrict__ dst,
                                 const int* __restrict__ flag, int n) {
    int i = blockIdx.x * 256 + threadIdx.x;
    if (i >= n) return;
    if (flag[0]) ((unsigned short*)dst)[i] = f2bf(src[i]);
    else         ((float*)dst)[i] = src[i];
}

// ---- fused convert + transpose: dst(N,K) bf16 <- src(K,N) elem offset `off` ----
__global__ __launch_bounds__(256)
void transpose_w_kernel(const void* __restrict__ src, unsigned short* __restrict__ dst,
                        const int* __restrict__ flag, int N, int K, long long off) {
    __shared__ float tile[32][33];
    int n0 = blockIdx.x * 32, k0 = blockIdx.y * 32;
    int r = threadIdx.x >> 5;      // 0..7
    int c = threadIdx.x & 31;
    #pragma unroll
    for (int rr = 0; rr < 4; ++rr) {
        int k = k0 + r + rr * 8;
        long long j = off + (long long)k * N + n0 + c;
        tile[r + rr * 8][c] = flag[0] ? bf2f(((const unsigned short*)src)[j])
                                      : ((const float*)src)[j];
    }
    __syncthreads();
    #pragma unroll
    for (int rr = 0; rr < 4; ++rr) {
        int n = n0 + r + rr * 8;
        dst[(size_t)n * K + k0 + c] = f2bf(tile[c][r + rr * 8]);
    }
}

// ---- block reduction (blockDim.x == 256) ----
__device__ __forceinline__ float blk_sum256(float v, float* red) {
    #pragma unroll
    for (int off = 32; off; off >>= 1) v += __shfl_down(v, off, 64);
    int tid = threadIdx.x;
    __syncthreads();
    if ((tid & 63) == 0) red[tid >> 6] = v;
    __syncthreads();
    return red[0] + red[1] + red[2] + red[3];
}

// ---- AdaLN: h = (exp(loggamma)*[2*(1-0.1*hn)*hn] + beta) * m ----
__global__ __launch_bounds__(256)
void adaln_kernel(const float* __restrict__ x,
                  const float* __restrict__ emb,
                  const int* __restrict__ lvl,
                  const float* __restrict__ mvec,
                  unsigned short* __restrict__ h) {
    __shared__ float red[4];
    int row = blockIdx.x;
    int b = row / TT;
    int tid = threadIdx.x;
    const float* xr = x + (size_t)row * D_MODEL;

    float s = 0.f;
    for (int j = tid; j < D_MODEL; j += 256) s += xr[j];
    float mu = blk_sum256(s, red) * (1.0f / D_MODEL);

    float vs = 0.f;
    for (int j = tid; j < D_MODEL; j += 256) { float d = xr[j] - mu; vs += d * d; }
    float var = blk_sum256(vs, red) * (1.0f / D_MODEL);
    float rstd = rsqrtf(var + EPSV);

    int lv = lvl[b];
    const float* g = emb + (size_t)lv * (2 * D_MODEL);
    float mval = mvec[row];
    unsigned short* hr = h + (size_t)row * D_MODEL;
    for (int j = tid; j < D_MODEL; j += 256) {
        float hn = (xr[j] - mu) * rstd;
        float h2 = 2.0f * (1.0f - 0.1f * hn) * hn;
        float o = __expf(g[j]) * h2 + g[D_MODEL + j];
        hr[j] = f2bf(o * mval);
    }
}

// ---- m97-style MFMA GEMM: C(MxN) = A(MxK) @ BT(NxK)^T, fused epilogues ----
// BM = 128, BN = NI*32 (NI=4 -> 128, NI=2 -> 64). BK=32, single-buffered,
// global_load_lds width 16, pad-free LDS (layout == lane order).
#define EPI_STORE 0
#define EPI_GELU  1
#define EPI_RESID 2

template<int MI, int NI>
__global__ __launch_bounds__(256)
void gemm_mfma_kernel(const unsigned short* __restrict__ A,
                      const unsigned short* __restrict__ BT,
                      const float* __restrict__ bias,
                      unsigned short* __restrict__ outb,
                      const float* __restrict__ xin,
                      float* __restrict__ xout,
                      const float* __restrict__ mvec,
                      int M, int N, int K, int mode) {
    constexpr int BM = 2 * MI * 16;      // 128
    constexpr int BN = 2 * NI * 16;      // 128 or 64
    __shared__ __align__(16) unsigned short As[BM * 32];
    __shared__ __align__(16) unsigned short Bs[BN * 32];
    int tid = threadIdx.x;
    int wave = tid >> 6;
    int lane = tid & 63;
    int quad = lane >> 4;
    int l16  = lane & 15;
    int tileM = blockIdx.y * BM;
    int tileN = blockIdx.x * BN;
    int wm = (wave & 1) * MI * 16;
    int wn = (wave >> 1) * NI * 16;

    f32x4 acc[MI][NI] = {};

    int lrow = lane >> 2;          // 0..15
    int lcol = (lane & 3) * 8;     // 0,8,16,24

    const unsigned short* Abase = A  + (size_t)(tileM + lrow) * K + lcol;
    const unsigned short* Bbase = BT + (size_t)(tileN + lrow) * K + lcol;

    for (int k0 = 0; k0 < K; k0 += 32) {
        #pragma unroll
        for (int q = 0; q < BM / 64; ++q) {
            int inst = wave * (BM / 64) + q;
            gl_lds16(Abase + (size_t)(inst * 16) * K + k0, &As[inst * 512]);
        }
        #pragma unroll
        for (int q = 0; q < BN / 64; ++q) {
            int inst = wave * (BN / 64) + q;
            gl_lds16(Bbase + (size_t)(inst * 16) * K + k0, &Bs[inst * 512]);
        }
        __syncthreads();

        bf16x8 af[MI], bf[NI];
        #pragma unroll
        for (int mi = 0; mi < MI; ++mi)
            af[mi] = *(const bf16x8*)(&As[(wm + mi * 16 + l16) * 32 + quad * 8]);
        #pragma unroll
        for (int ni = 0; ni < NI; ++ni)
            bf[ni] = *(const bf16x8*)(&Bs[(wn + ni * 16 + l16) * 32 + quad * 8]);
        #pragma unroll
        for (int mi = 0; mi < MI; ++mi)
            #pragma unroll
            for (int ni = 0; ni < NI; ++ni)
                acc[mi][ni] = __builtin_amdgcn_mfma_f32_16x16x32_bf16(af[mi], bf[ni], acc[mi][ni], 0, 0, 0);
        __syncthreads();
    }

    #pragma unroll
    for (int mi = 0; mi < MI; ++mi)
    #pragma unroll
    for (int ni = 0; ni < NI; ++ni) {
        #pragma unroll
        for (int r = 0; r < 4; ++r) {
            int row = tileM + wm + mi * 16 + quad * 4 + r;
            int col = tileN + wn + ni * 16 + l16;
            float v = acc[mi][ni][r];
            if (bias) v += bias[col];
            size_t idx = (size_t)row * N + col;
            if (mode == EPI_STORE) {
                outb[idx] = f2bf(v);
            } else if (mode == EPI_GELU) {
                float gel = 0.5f * v * (1.0f + erff(v * 0.70710678118654752f));
                outb[idx] = f2bf(gel);
            } else {
                float mval = mvec[row];
                xout[idx] = (xin[idx] + v) * mval;
            }
        }
    }
}

// ---- flash attention (unchanged from R3, verified) ----
#define FA_DPAD 72

__global__ __launch_bounds__(256)
void fattn_kernel(const unsigned short* __restrict__ qkv,
                  unsigned short* __restrict__ o) {
    __shared__ __align__(16) unsigned short Qs[64 * FA_DPAD];
    __shared__ __align__(16) unsigned short Ks[64 * FA_DPAD];
    __shared__ __align__(16) unsigned short Vs[64 * FA_DPAD];
    __shared__ __align__(16) unsigned short Ps[64 * FA_DPAD];

    int qt  = blockIdx.x;
    int hd  = blockIdx.y;
    int b   = blockIdx.z;
    int tid = threadIdx.x;
    int wave = tid >> 6;
    int lane = tid & 63;
    int quad = lane >> 4;
    int l16  = lane & 15;

    const unsigned short* base = qkv + (size_t)b * TT * 3072;

    {
        int r = tid >> 2, c = (tid & 3) * 16;
        const unsigned short* src = base + (size_t)(qt * 64 + r) * 3072 + hd * DH + c;
        *(uint4*)(&Qs[r * FA_DPAD + c])     = *(const uint4*)(src);
        *(uint4*)(&Qs[r * FA_DPAD + c + 8]) = *(const uint4*)(src + 8);
    }
    __syncthreads();

    bf16x8 aq[2];
    #pragma unroll
    for (int cc = 0; cc < 2; ++cc)
        aq[cc] = *(const bf16x8*)(&Qs[(wave * 16 + l16) * FA_DPAD + cc * 32 + quad * 8]);

    f32x4 Oacc[4] = {};
    float mstate[4], lstate[4];
    #pragma unroll
    for (int r = 0; r < 4; ++r) { mstate[r] = -1e30f; lstate[r] = 0.f; }

    for (int jt = 0; jt <= qt; ++jt) {
        __syncthreads();
        {
            int r = tid >> 2, c = (tid & 3) * 16;
            const unsigned short* src = base + (size_t)(jt * 64 + r) * 3072 + 1024 + hd * DH + c;
            *(uint4*)(&Ks[r * FA_DPAD + c])     = *(const uint4*)(src);
            *(uint4*)(&Ks[r * FA_DPAD + c + 8]) = *(const uint4*)(src + 8);
        }
        {
            int j = lane, c = wave * 16;
            const unsigned short* src = base + (size_t)(jt * 64 + j) * 3072 + 2048 + hd * DH + c;
            unsigned short tmp[16];
            *(uint4*)(tmp)     = *(const uint4*)(src);
            *(uint4*)(tmp + 8) = *(const uint4*)(src + 8);
            #pragma unroll
            for (int d = 0; d < 16; ++d) Vs[(c + d) * FA_DPAD + j] = tmp[d];
        }
        __syncthreads();

        f32x4 S[4] = {};
        #pragma unroll
        for (int t = 0; t < 4; ++t)
            #pragma unroll
            for (int cc = 0; cc < 2; ++cc) {
                bf16x8 bk = *(const bf16x8*)(&Ks[(t * 16 + l16) * FA_DPAD + cc * 32 + quad * 8]);
                S[t] = __builtin_amdgcn_mfma_f32_16x16x32_bf16(aq[cc], bk, S[t], 0, 0, 0);
            }

        int qrow0 = qt * 64 + wave * 16 + quad * 4;
        bool diag = (jt == qt);
        float mnew[4];
        #pragma unroll
        for (int r = 0; r < 4; ++r) {
            float v = -1e30f;
            #pragma unroll
            for (int t = 0; t < 4; ++t) {
                float s = S[t][r] * 0.125f;
                if (diag) {
                    int j = jt * 64 + t * 16 + l16;
                    if (j > qrow0 + r) s = -1e30f;
                }
                S[t][r] = s;
                v = fmaxf(v, s);
            }
            v = fmaxf(v, __shfl_xor(v, 1, 64));
            v = fmaxf(v, __shfl_xor(v, 2, 64));
            v = fmaxf(v, __shfl_xor(v, 4, 64));
            v = fmaxf(v, __shfl_xor(v, 8, 64));
            mnew[r] = fmaxf(mstate[r], v);
        }

        #pragma unroll
        for (int r = 0; r < 4; ++r) {
            float rs = 0.f;
            #pragma unroll
            for (int t = 0; t < 4; ++t) {
                float p = __expf(S[t][r] - mnew[r]);
                rs += p;
                Ps[(wave * 16 + quad * 4 + r) * FA_DPAD + t * 16 + l16] = f2bf(p);
            }
            rs += __shfl_xor(rs, 1, 64);
            rs += __shfl_xor(rs, 2, 64);
            rs += __shfl_xor(rs, 4, 64);
            rs += __shfl_xor(rs, 8, 64);
            float alpha = __expf(mstate[r] - mnew[r]);
            lstate[r] = alpha * lstate[r] + rs;
            mstate[r] = mnew[r];
            #pragma unroll
            for (int t = 0; t < 4; ++t) Oacc[t][r] *= alpha;
        }

        #pragma unroll
        for (int cc = 0; cc < 2; ++cc) {
            bf16x8 ap = *(const bf16x8*)(&Ps[(wave * 16 + l16) * FA_DPAD + cc * 32 + quad * 8]);
            #pragma unroll
            for (int t = 0; t < 4; ++t) {
                bf16x8 bv = *(const bf16x8*)(&Vs[(t * 16 + l16) * FA_DPAD + cc * 32 + quad * 8]);
                Oacc[t] = __builtin_amdgcn_mfma_f32_16x16x32_bf16(ap, bv, Oacc[t], 0, 0, 0);
            }
        }
    }

    #pragma unroll
    for (int r = 0; r < 4; ++r) {
        float inv = 1.0f / lstate[r];
        int qi = qt * 64 + wave * 16 + quad * 4 + r;
        unsigned short* orow = o + (size_t)(b * TT + qi) * D_MODEL + hd * DH;
        #pragma unroll
        for (int t = 0; t < 4; ++t)
            orow[t * 16 + l16] = f2bf(Oacc[t][r] * inv);
    }
}

// ---- workspace layout (bytes) ----
#define MB (1048576u)
#define WS_FLAG   0u
#define WS_MF     4096u
#define WS_EMBA   (WS_MF + 8192u)
#define WS_EMBF   (WS_EMBA + 262144u)
#define WS_BOUT   (WS_EMBF + 262144u)
#define WS_B1     (WS_BOUT + 16384u)
#define WS_B2     (WS_B1 + 65536u)
#define WS_XF     (1u*MB)                  // 8 MB fp32
#define WS_H      (9u*MB)                  // 4 MB bf16
#define WS_QKV    (13u*MB)                 // 12 MB bf16
#define WS_OB     (25u*MB)                 // 4 MB bf16
#define WS_FF1    (29u*MB)                 // 16 MB bf16
#define WS_WQKV   (45u*MB)                 // 6 MB bf16 transposed (3072 x 1024)
#define WS_WOUT   (51u*MB)                 // 2 MB (1024 x 1024)
#define WS_W1     (53u*MB)                 // 8 MB (4096 x 1024)
#define WS_W2     (61u*MB)                 // 8 MB (1024 x 4096)  end: 69 MB

extern "C" void kernel_launch(void* const* d_in, const int* in_sizes, int n_in,
                              void* d_out, int out_size, void* d_ws, size_t ws_size,
                              hipStream_t stream) {
    const void* x_in  = d_in[0];
    const void* m_in  = d_in[1];
    const int*  l_in  = (const int*)d_in[2];
    const void* Wqkv  = d_in[3];
    const void* Wout  = d_in[4];
    const void* boutp = d_in[5];
    const void* ada_a = d_in[6];
    const void* ada_f = d_in[7];
    const void* W1    = d_in[8];
    const void* b1    = d_in[9];
    const void* W2    = d_in[10];
    const void* b2    = d_in[11];

    char* ws = (char*)d_ws;
    int*            flag = (int*)(ws + WS_FLAG);
    float*          mf   = (float*)(ws + WS_MF);
    float*          embA = (float*)(ws + WS_EMBA);
    float*          embF = (float*)(ws + WS_EMBF);
    float*          boutf= (float*)(ws + WS_BOUT);
    float*          b1f  = (float*)(ws + WS_B1);
    float*          b2f  = (float*)(ws + WS_B2);
    float*          xf   = (float*)(ws + WS_XF);
    unsigned short* h    = (unsigned short*)(ws + WS_H);
    unsigned short* qkv  = (unsigned short*)(ws + WS_QKV);
    unsigned short* ob   = (unsigned short*)(ws + WS_OB);
    unsigned short* ff1  = (unsigned short*)(ws + WS_FF1);
    unsigned short* wqkvt= (unsigned short*)(ws + WS_WQKV);
    unsigned short* woutt= (unsigned short*)(ws + WS_WOUT);
    unsigned short* w1t  = (unsigned short*)(ws + WS_W1);
    unsigned short* w2t  = (unsigned short*)(ws + WS_W2);

    const int n = MM * D_MODEL;

    detect_kernel<<<1, 256, 0, stream>>>((const unsigned short*)x_in, flag);

    load_f32_kernel<<<n / 256, 256, 0, stream>>>(x_in, xf, flag, n);
    load_f32_kernel<<<MM / 256, 256, 0, stream>>>(m_in, mf, flag, MM);
    load_f32_kernel<<<65536 / 256, 256, 0, stream>>>(ada_a, embA, flag, 65536);
    load_f32_kernel<<<65536 / 256, 256, 0, stream>>>(ada_f, embF, flag, 65536);
    load_f32_kernel<<<4096 / 256, 256, 0, stream>>>(boutp, boutf, flag, 4096);
    load_f32_kernel<<<16384 / 256, 256, 0, stream>>>(b1, b1f, flag, 16384);
    load_f32_kernel<<<4096 / 256, 256, 0, stream>>>(b2, b2f, flag, 4096);

    const long long nqkv = (long long)D_MODEL * 3 * D_MODEL;
    const long long nsq  = (long long)D_MODEL * D_MODEL;
    const long long nw1  = (long long)D_MODEL * 4 * D_MODEL;

    for (int i = 0; i < N_LAYERS; ++i) {
        // weights -> bf16, transposed to (N, K)
        transpose_w_kernel<<<dim3(3072 / 32, 1024 / 32), 256, 0, stream>>>(Wqkv, wqkvt, flag, 3072, 1024, i * nqkv);
        transpose_w_kernel<<<dim3(1024 / 32, 1024 / 32), 256, 0, stream>>>(Wout, woutt, flag, 1024, 1024, i * nsq);
        transpose_w_kernel<<<dim3(4096 / 32, 1024 / 32), 256, 0, stream>>>(W1,   w1t,   flag, 4096, 1024, i * nw1);
        transpose_w_kernel<<<dim3(1024 / 32, 4096 / 32), 256, 0, stream>>>(W2,   w2t,   flag, 1024, 4096, i * nw1);

        // ---- attention sub-block ----
        adaln_kernel<<<MM, 256, 0, stream>>>(xf, embA + (size_t)i * N_LEVELS * 2 * D_MODEL, l_in, mf, h);
        gemm_mfma_kernel<4,4><<<dim3(3072 / 128, MM / 128), 256, 0, stream>>>(
            h, wqkvt, nullptr, qkv, nullptr, nullptr, nullptr, MM, 3072, 1024, EPI_STORE);
        fattn_kernel<<<dim3(TT / 64, N_HEADS, BB), 256, 0, stream>>>(qkv, ob);
        gemm_mfma_kernel<4,2><<<dim3(1024 / 64, MM / 128), 256, 0, stream>>>(
            ob, woutt, boutf + (size_t)i * D_MODEL, nullptr, xf, xf, mf, MM, 1024, 1024, EPI_RESID);
        // ---- FFN sub-block ----
        adaln_kernel<<<MM, 256, 0, stream>>>(xf, embF + (size_t)i * N_LEVELS * 2 * D_MODEL, l_in, mf, h);
        gemm_mfma_kernel<4,4><<<dim3(4096 / 128, MM / 128), 256, 0, stream>>>(
            h, w1t, b1f + (size_t)i * 4 * D_MODEL, ff1, nullptr, nullptr, nullptr, MM, 4096, 1024, EPI_GELU);
        gemm_mfma_kernel<4,2><<<dim3(1024 / 64, MM / 128), 256, 0, stream>>>(
            ff1, w2t, b2f + (size_t)i * D_MODEL, nullptr, xf, xf, mf, MM, 1024, 4096, EPI_RESID);
    }

    store_out_kernel<<<n / 256, 256, 0, stream>>>(xf, d_out, flag, n);
}

// Round 5
// 1057.168 us; speedup vs baseline: 6.4914x; 1.2665x over previous
//
#include <hip/hip_runtime.h>

#define D_MODEL 1024
#define N_HEADS 16
#define DH 64
#define N_LAYERS 4
#define N_LEVELS 8
#define BB 2
#define TT 1024
#define MM (BB*TT)
#define EPSV 1e-5f

typedef float f32x4 __attribute__((ext_vector_type(4)));
typedef short bf16x8 __attribute__((ext_vector_type(8)));

__device__ __forceinline__ float bf2f(unsigned short u) {
    union { unsigned int i; float f; } c; c.i = ((unsigned int)u) << 16; return c.f;
}
__device__ __forceinline__ unsigned short f2bf(float f) {
    union { float f; unsigned int i; } c; c.f = f;
    unsigned int x = c.i;
    return (unsigned short)((x + 0x7fffu + ((x >> 16) & 1u)) >> 16);  // RNE
}
__device__ __forceinline__ float cvt_in(const void* src, long long j, int isbf) {
    return isbf ? bf2f(((const unsigned short*)src)[j]) : ((const float*)src)[j];
}

// async global->LDS, 16 B per lane; LDS dest = wave-uniform base + lane*16
__device__ __forceinline__ void gl_lds16(const unsigned short* g, unsigned short* l) {
    __builtin_amdgcn_global_load_lds(
        (const __attribute__((address_space(1))) unsigned int*)g,
        (__attribute__((address_space(3))) unsigned int*)l,
        16, 0, 0);
}

// ---- dtype detection (fp32 vs bf16 input buffers) ----
__global__ void detect_kernel(const unsigned short* __restrict__ x, int* __restrict__ flag) {
    __shared__ int cnts[256];
    int cnt = 0;
    for (int i = threadIdx.x; i < 16384; i += 256) {
        unsigned short u = x[2 * i];
        int e = (u >> 7) & 0xFF;
        if (e >= 110 && e <= 140) cnt++;
    }
    cnts[threadIdx.x] = cnt;
    __syncthreads();
    for (int s = 128; s; s >>= 1) {
        if (threadIdx.x < s) cnts[threadIdx.x] += cnts[threadIdx.x + s];
        __syncthreads();
    }
    if (threadIdx.x == 0) flag[0] = (cnts[0] > 12000) ? 1 : 0;
}

// ---- converters ----
__global__ void load_f32_kernel(const void* __restrict__ src, float* __restrict__ dst,
                                const int* __restrict__ flag, int n) {
    int i = blockIdx.x * 256 + threadIdx.x;
    if (i >= n) return;
    dst[i] = cvt_in(src, i, flag[0]);
}
__global__ void store_out_kernel(const float* __restrict__ src, void* __restrict__ dst,
                                 const int* __restrict__ flag, int n) {
    int i = blockIdx.x * 256 + threadIdx.x;
    if (i >= n) return;
    if (flag[0]) ((unsigned short*)dst)[i] = f2bf(src[i]);
    else         ((float*)dst)[i] = src[i];
}
// fused small-tensor converts: m, adaln_attn, adaln_ffn, bout, b1, b2
__global__ void load_small_kernel(const void* m_in, const void* aa, const void* af_,
                                  const void* bo, const void* b1, const void* b2,
                                  float* mf, float* embA, float* embF,
                                  float* boutf, float* b1f, float* b2f,
                                  const int* __restrict__ flag) {
    int i = blockIdx.x * 256 + threadIdx.x;
    int isbf = flag[0];
    if (i < 2048)        mf[i] = cvt_in(m_in, i, isbf);
    else if (i < 67584)  embA[i - 2048] = cvt_in(aa, i - 2048, isbf);
    else if (i < 133120) embF[i - 67584] = cvt_in(af_, i - 67584, isbf);
    else if (i < 137216) boutf[i - 133120] = cvt_in(bo, i - 133120, isbf);
    else if (i < 153600) b1f[i - 137216] = cvt_in(b1, i - 137216, isbf);
    else if (i < 157696) b2f[i - 153600] = cvt_in(b2, i - 153600, isbf);
}

// ---- per-layer fused weight transpose: dst(N,K) bf16 <- src(K,N) ----
__global__ __launch_bounds__(256)
void transpose_layer_kernel(const void* Wqkv, const void* Wo, const void* W1, const void* W2,
                            unsigned short* wq, unsigned short* wo,
                            unsigned short* w1, unsigned short* w2,
                            const int* __restrict__ flag,
                            long long o_qkv, long long o_o, long long o_1, long long o_2) {
    __shared__ float tile[32][33];
    int bid = blockIdx.x;
    const void* src; unsigned short* dst; long long off; int N, K, nt, kt;
    if (bid < 3072)      { int t = bid;        src = Wqkv; dst = wq; off = o_qkv; N = 3072; K = 1024; nt = t % 96;  kt = t / 96; }
    else if (bid < 4096) { int t = bid - 3072; src = Wo;   dst = wo; off = o_o;   N = 1024; K = 1024; nt = t % 32;  kt = t / 32; }
    else if (bid < 8192) { int t = bid - 4096; src = W1;   dst = w1; off = o_1;   N = 4096; K = 1024; nt = t % 128; kt = t / 128; }
    else                 { int t = bid - 8192; src = W2;   dst = w2; off = o_2;   N = 1024; K = 4096; nt = t % 32;  kt = t / 32; }
    int n0 = nt * 32, k0 = kt * 32;
    int r = threadIdx.x >> 5, c = threadIdx.x & 31;
    int isbf = flag[0];
    #pragma unroll
    for (int rr = 0; rr < 4; ++rr) {
        int k = k0 + r + rr * 8;
        tile[r + rr * 8][c] = cvt_in(src, off + (long long)k * N + n0 + c, isbf);
    }
    __syncthreads();
    #pragma unroll
    for (int rr = 0; rr < 4; ++rr) {
        int n = n0 + r + rr * 8;
        dst[(size_t)n * K + k0 + c] = f2bf(tile[c][r + rr * 8]);
    }
}

// ---- block reduction (blockDim.x == 256) ----
__device__ __forceinline__ float blk_sum256(float v, float* red) {
    #pragma unroll
    for (int off = 32; off; off >>= 1) v += __shfl_down(v, off, 64);
    int tid = threadIdx.x;
    __syncthreads();
    if ((tid & 63) == 0) red[tid >> 6] = v;
    __syncthreads();
    return red[0] + red[1] + red[2] + red[3];
}

// ---- AdaLN ----
__global__ __launch_bounds__(256)
void adaln_kernel(const float* __restrict__ x,
                  const float* __restrict__ emb,
                  const int* __restrict__ lvl,
                  const float* __restrict__ mvec,
                  unsigned short* __restrict__ h) {
    __shared__ float red[4];
    int row = blockIdx.x;
    int b = row / TT;
    int tid = threadIdx.x;
    const float* xr = x + (size_t)row * D_MODEL;

    float s = 0.f;
    for (int j = tid; j < D_MODEL; j += 256) s += xr[j];
    float mu = blk_sum256(s, red) * (1.0f / D_MODEL);

    float vs = 0.f;
    for (int j = tid; j < D_MODEL; j += 256) { float d = xr[j] - mu; vs += d * d; }
    float var = blk_sum256(vs, red) * (1.0f / D_MODEL);
    float rstd = rsqrtf(var + EPSV);

    int lv = lvl[b];
    const float* g = emb + (size_t)lv * (2 * D_MODEL);
    float mval = mvec[row];
    unsigned short* hr = h + (size_t)row * D_MODEL;
    for (int j = tid; j < D_MODEL; j += 256) {
        float hn = (xr[j] - mu) * rstd;
        float h2 = 2.0f * (1.0f - 0.1f * hn) * hn;
        float o = __expf(g[j]) * h2 + g[D_MODEL + j];
        hr[j] = f2bf(o * mval);
    }
}

// ---- 8-wave MFMA GEMM: C(MxN) = A(MxK)@BT(NxK)^T; BM=WR*MI*16, BN=WC*NI*16 ----
// blockIdx.z = split-K chunk (A/BT advanced by z*K elems along lda/ldb).
#define EPI_STORE 0
#define EPI_GELU  1
#define EPI_RESID 2
#define EPI_PART  3

template<int MI, int NI, int WR, int WC>
__global__ __launch_bounds__(512)
void gemm8_kernel(const unsigned short* __restrict__ A, int lda,
                  const unsigned short* __restrict__ BT, int ldb,
                  const float* __restrict__ bias,
                  unsigned short* __restrict__ outb,
                  const float* __restrict__ xin,
                  float* __restrict__ xout,
                  const float* __restrict__ mvec,
                  float* __restrict__ pbuf,
                  int M, int N, int K, int mode) {
    constexpr int BM = WR * MI * 16;   // 128
    constexpr int BN = WC * NI * 16;   // 128 or 64
    __shared__ __align__(16) unsigned short As[BM * 32];
    __shared__ __align__(16) unsigned short Bs[BN * 32];
    int tid = threadIdx.x;
    int wave = tid >> 6;               // 0..7
    int lane = tid & 63;
    int quad = lane >> 4;
    int l16  = lane & 15;
    int tileM = blockIdx.y * BM;
    int tileN = blockIdx.x * BN;
    int wm = (wave % WR) * MI * 16;
    int wn = (wave / WR) * NI * 16;

    f32x4 acc[MI][NI] = {};

    long long zoff = (long long)blockIdx.z * K;
    const unsigned short* Abase = A  + zoff + (size_t)(tileM + wave * 16 + (lane >> 2)) * lda + (lane & 3) * 8;
    const unsigned short* Bbase = BT + zoff + (size_t)(tileN + (wave % (BN / 16)) * 16 + (lane >> 2)) * ldb + (lane & 3) * 8;

    for (int k0 = 0; k0 < K; k0 += 32) {
        gl_lds16(Abase + k0, &As[wave * 512]);
        if (wave < BN / 16) gl_lds16(Bbase + k0, &Bs[wave * 512]);
        __syncthreads();

        bf16x8 af[MI], bf[NI];
        #pragma unroll
        for (int mi = 0; mi < MI; ++mi)
            af[mi] = *(const bf16x8*)(&As[(wm + mi * 16 + l16) * 32 + quad * 8]);
        #pragma unroll
        for (int ni = 0; ni < NI; ++ni)
            bf[ni] = *(const bf16x8*)(&Bs[(wn + ni * 16 + l16) * 32 + quad * 8]);
        #pragma unroll
        for (int mi = 0; mi < MI; ++mi)
            #pragma unroll
            for (int ni = 0; ni < NI; ++ni)
                acc[mi][ni] = __builtin_amdgcn_mfma_f32_16x16x32_bf16(af[mi], bf[ni], acc[mi][ni], 0, 0, 0);
        __syncthreads();
    }

    #pragma unroll
    for (int mi = 0; mi < MI; ++mi)
    #pragma unroll
    for (int ni = 0; ni < NI; ++ni) {
        #pragma unroll
        for (int r = 0; r < 4; ++r) {
            int row = tileM + wm + mi * 16 + quad * 4 + r;
            int col = tileN + wn + ni * 16 + l16;
            float v = acc[mi][ni][r];
            size_t idx = (size_t)row * N + col;
            if (mode == EPI_STORE) {
                outb[idx] = f2bf(v);
            } else if (mode == EPI_GELU) {
                v += bias[col];
                float gel = 0.5f * v * (1.0f + erff(v * 0.70710678118654752f));
                outb[idx] = f2bf(gel);
            } else if (mode == EPI_RESID) {
                v += bias[col];
                xout[idx] = (xin[idx] + v) * mvec[row];
            } else {  // EPI_PART: fp32 partial per chunk
                pbuf[(size_t)blockIdx.z * M * N + idx] = v;
            }
        }
    }
}

// combine 2 split-K partials + bias + residual + mask
__global__ void combine2_kernel(float* __restrict__ xf,
                                const float* __restrict__ pbuf,
                                const float* __restrict__ bias,
                                const float* __restrict__ mvec, int n) {
    int i = blockIdx.x * 256 + threadIdx.x;
    if (i >= n) return;
    int row = i >> 10, col = i & 1023;
    xf[i] = (xf[i] + pbuf[i] + pbuf[n + i] + bias[col]) * mvec[row];
}

// ---- flash attention (verified R3/R4) ----
#define FA_DPAD 72

__global__ __launch_bounds__(256)
void fattn_kernel(const unsigned short* __restrict__ qkv,
                  unsigned short* __restrict__ o) {
    __shared__ __align__(16) unsigned short Qs[64 * FA_DPAD];
    __shared__ __align__(16) unsigned short Ks[64 * FA_DPAD];
    __shared__ __align__(16) unsigned short Vs[64 * FA_DPAD];
    __shared__ __align__(16) unsigned short Ps[64 * FA_DPAD];

    int qt  = blockIdx.x;
    int hd  = blockIdx.y;
    int b   = blockIdx.z;
    int tid = threadIdx.x;
    int wave = tid >> 6;
    int lane = tid & 63;
    int quad = lane >> 4;
    int l16  = lane & 15;

    const unsigned short* base = qkv + (size_t)b * TT * 3072;

    {
        int r = tid >> 2, c = (tid & 3) * 16;
        const unsigned short* src = base + (size_t)(qt * 64 + r) * 3072 + hd * DH + c;
        *(uint4*)(&Qs[r * FA_DPAD + c])     = *(const uint4*)(src);
        *(uint4*)(&Qs[r * FA_DPAD + c + 8]) = *(const uint4*)(src + 8);
    }
    __syncthreads();

    bf16x8 aq[2];
    #pragma unroll
    for (int cc = 0; cc < 2; ++cc)
        aq[cc] = *(const bf16x8*)(&Qs[(wave * 16 + l16) * FA_DPAD + cc * 32 + quad * 8]);

    f32x4 Oacc[4] = {};
    float mstate[4], lstate[4];
    #pragma unroll
    for (int r = 0; r < 4; ++r) { mstate[r] = -1e30f; lstate[r] = 0.f; }

    for (int jt = 0; jt <= qt; ++jt) {
        __syncthreads();
        {
            int r = tid >> 2, c = (tid & 3) * 16;
            const unsigned short* src = base + (size_t)(jt * 64 + r) * 3072 + 1024 + hd * DH + c;
            *(uint4*)(&Ks[r * FA_DPAD + c])     = *(const uint4*)(src);
            *(uint4*)(&Ks[r * FA_DPAD + c + 8]) = *(const uint4*)(src + 8);
        }
        {
            int j = lane, c = wave * 16;
            const unsigned short* src = base + (size_t)(jt * 64 + j) * 3072 + 2048 + hd * DH + c;
            unsigned short tmp[16];
            *(uint4*)(tmp)     = *(const uint4*)(src);
            *(uint4*)(tmp + 8) = *(const uint4*)(src + 8);
            #pragma unroll
            for (int d = 0; d < 16; ++d) Vs[(c + d) * FA_DPAD + j] = tmp[d];
        }
        __syncthreads();

        f32x4 S[4] = {};
        #pragma unroll
        for (int t = 0; t < 4; ++t)
            #pragma unroll
            for (int cc = 0; cc < 2; ++cc) {
                bf16x8 bk = *(const bf16x8*)(&Ks[(t * 16 + l16) * FA_DPAD + cc * 32 + quad * 8]);
                S[t] = __builtin_amdgcn_mfma_f32_16x16x32_bf16(aq[cc], bk, S[t], 0, 0, 0);
            }

        int qrow0 = qt * 64 + wave * 16 + quad * 4;
        bool diag = (jt == qt);
        float mnew[4];
        #pragma unroll
        for (int r = 0; r < 4; ++r) {
            float v = -1e30f;
            #pragma unroll
            for (int t = 0; t < 4; ++t) {
                float s = S[t][r] * 0.125f;
                if (diag) {
                    int j = jt * 64 + t * 16 + l16;
                    if (j > qrow0 + r) s = -1e30f;
                }
                S[t][r] = s;
                v = fmaxf(v, s);
            }
            v = fmaxf(v, __shfl_xor(v, 1, 64));
            v = fmaxf(v, __shfl_xor(v, 2, 64));
            v = fmaxf(v, __shfl_xor(v, 4, 64));
            v = fmaxf(v, __shfl_xor(v, 8, 64));
            mnew[r] = fmaxf(mstate[r], v);
        }

        #pragma unroll
        for (int r = 0; r < 4; ++r) {
            float rs = 0.f;
            #pragma unroll
            for (int t = 0; t < 4; ++t) {
                float p = __expf(S[t][r] - mnew[r]);
                rs += p;
                Ps[(wave * 16 + quad * 4 + r) * FA_DPAD + t * 16 + l16] = f2bf(p);
            }
            rs += __shfl_xor(rs, 1, 64);
            rs += __shfl_xor(rs, 2, 64);
            rs += __shfl_xor(rs, 4, 64);
            rs += __shfl_xor(rs, 8, 64);
            float alpha = __expf(mstate[r] - mnew[r]);
            lstate[r] = alpha * lstate[r] + rs;
            mstate[r] = mnew[r];
            #pragma unroll
            for (int t = 0; t < 4; ++t) Oacc[t][r] *= alpha;
        }

        #pragma unroll
        for (int cc = 0; cc < 2; ++cc) {
            bf16x8 ap = *(const bf16x8*)(&Ps[(wave * 16 + l16) * FA_DPAD + cc * 32 + quad * 8]);
            #pragma unroll
            for (int t = 0; t < 4; ++t) {
                bf16x8 bv = *(const bf16x8*)(&Vs[(t * 16 + l16) * FA_DPAD + cc * 32 + quad * 8]);
                Oacc[t] = __builtin_amdgcn_mfma_f32_16x16x32_bf16(ap, bv, Oacc[t], 0, 0, 0);
            }
        }
    }

    #pragma unroll
    for (int r = 0; r < 4; ++r) {
        float inv = 1.0f / lstate[r];
        int qi = qt * 64 + wave * 16 + quad * 4 + r;
        unsigned short* orow = o + (size_t)(b * TT + qi) * D_MODEL + hd * DH;
        #pragma unroll
        for (int t = 0; t < 4; ++t)
            orow[t * 16 + l16] = f2bf(Oacc[t][r] * inv);
    }
}

// ---- workspace layout (bytes) ----
#define MB (1048576u)
#define WS_FLAG   0u
#define WS_MF     4096u
#define WS_EMBA   (WS_MF + 8192u)
#define WS_EMBF   (WS_EMBA + 262144u)
#define WS_BOUT   (WS_EMBF + 262144u)
#define WS_B1     (WS_BOUT + 16384u)
#define WS_B2     (WS_B1 + 65536u)
#define WS_XF     (1u*MB)    // 8 MB fp32
#define WS_H      (9u*MB)    // 4 MB bf16  | h/qkv/ob region doubles as W2
#define WS_QKV    (13u*MB)   // 12 MB bf16 | split-K partials (16 MB, 9..25)
#define WS_OB     (25u*MB)   // 4 MB bf16
#define WS_PART   (9u*MB)    // 2 x 8 MB fp32 partials (dead h/qkv space)
#define WS_FF1    (29u*MB)   // 16 MB bf16
#define WS_WQKV   (45u*MB)   // 6 MB (3072 x 1024)
#define WS_WOUT   (51u*MB)   // 2 MB (1024 x 1024)
#define WS_W1     (53u*MB)   // 8 MB (4096 x 1024)
#define WS_W2     (61u*MB)   // 8 MB (1024 x 4096)  end: 69 MB

extern "C" void kernel_launch(void* const* d_in, const int* in_sizes, int n_in,
                              void* d_out, int out_size, void* d_ws, size_t ws_size,
                              hipStream_t stream) {
    const void* x_in  = d_in[0];
    const void* m_in  = d_in[1];
    const int*  l_in  = (const int*)d_in[2];
    const void* Wqkv  = d_in[3];
    const void* Wout  = d_in[4];
    const void* boutp = d_in[5];
    const void* ada_a = d_in[6];
    const void* ada_f = d_in[7];
    const void* W1    = d_in[8];
    const void* b1    = d_in[9];
    const void* W2    = d_in[10];
    const void* b2    = d_in[11];

    char* ws = (char*)d_ws;
    int*            flag = (int*)(ws + WS_FLAG);
    float*          mf   = (float*)(ws + WS_MF);
    float*          embA = (float*)(ws + WS_EMBA);
    float*          embF = (float*)(ws + WS_EMBF);
    float*          boutf= (float*)(ws + WS_BOUT);
    float*          b1f  = (float*)(ws + WS_B1);
    float*          b2f  = (float*)(ws + WS_B2);
    float*          xf   = (float*)(ws + WS_XF);
    unsigned short* h    = (unsigned short*)(ws + WS_H);
    unsigned short* qkv  = (unsigned short*)(ws + WS_QKV);
    unsigned short* ob   = (unsigned short*)(ws + WS_OB);
    float*          part = (float*)(ws + WS_PART);
    unsigned short* ff1  = (unsigned short*)(ws + WS_FF1);
    unsigned short* wqkvt= (unsigned short*)(ws + WS_WQKV);
    unsigned short* woutt= (unsigned short*)(ws + WS_WOUT);
    unsigned short* w1t  = (unsigned short*)(ws + WS_W1);
    unsigned short* w2t  = (unsigned short*)(ws + WS_W2);

    const int n = MM * D_MODEL;

    detect_kernel<<<1, 256, 0, stream>>>((const unsigned short*)x_in, flag);
    load_f32_kernel<<<n / 256, 256, 0, stream>>>(x_in, xf, flag, n);
    load_small_kernel<<<(157696 + 255) / 256, 256, 0, stream>>>(
        m_in, ada_a, ada_f, boutp, b1, b2, mf, embA, embF, boutf, b1f, b2f, flag);

    const long long nqkv = (long long)D_MODEL * 3 * D_MODEL;
    const long long nsq  = (long long)D_MODEL * D_MODEL;
    const long long nw1  = (long long)D_MODEL * 4 * D_MODEL;

    for (int i = 0; i < N_LAYERS; ++i) {
        transpose_layer_kernel<<<12288, 256, 0, stream>>>(
            Wqkv, Wout, W1, W2, wqkvt, woutt, w1t, w2t, flag,
            i * nqkv, i * nsq, i * nw1, i * nw1);

        // ---- attention sub-block ----
        adaln_kernel<<<MM, 256, 0, stream>>>(xf, embA + (size_t)i * N_LEVELS * 2 * D_MODEL, l_in, mf, h);
        gemm8_kernel<4,2,2,4><<<dim3(3072 / 128, MM / 128), 512, 0, stream>>>(
            h, 1024, wqkvt, 1024, nullptr, qkv, nullptr, nullptr, nullptr, nullptr,
            MM, 3072, 1024, EPI_STORE);
        fattn_kernel<<<dim3(TT / 64, N_HEADS, BB), 256, 0, stream>>>(qkv, ob);
        gemm8_kernel<2,2,4,2><<<dim3(1024 / 64, MM / 128), 512, 0, stream>>>(
            ob, 1024, woutt, 1024, boutf + (size_t)i * D_MODEL, nullptr, xf, xf, mf, nullptr,
            MM, 1024, 1024, EPI_RESID);
        // ---- FFN sub-block ----
        adaln_kernel<<<MM, 256, 0, stream>>>(xf, embF + (size_t)i * N_LEVELS * 2 * D_MODEL, l_in, mf, h);
        gemm8_kernel<4,2,2,4><<<dim3(4096 / 128, MM / 128), 512, 0, stream>>>(
            h, 1024, w1t, 1024, b1f + (size_t)i * 4 * D_MODEL, ff1, nullptr, nullptr, nullptr, nullptr,
            MM, 4096, 1024, EPI_GELU);
        gemm8_kernel<2,2,4,2><<<dim3(1024 / 64, MM / 128, 2), 512, 0, stream>>>(
            ff1, 4096, w2t, 4096, nullptr, nullptr, nullptr, nullptr, nullptr, part,
            MM, 1024, 2048, EPI_PART);
        combine2_kernel<<<n / 256, 256, 0, stream>>>(
            xf, part, b2f + (size_t)i * D_MODEL, mf, n);
    }

    store_out_kernel<<<n / 256, 256, 0, stream>>>(xf, d_out, flag, n);
}

// Round 6
// 1021.486 us; speedup vs baseline: 6.7181x; 1.0349x over previous
//
#include <hip/hip_runtime.h>

#define D_MODEL 1024
#define N_HEADS 16
#define DH 64
#define N_LAYERS 4
#define N_LEVELS 8
#define BB 2
#define TT 1024
#define MM (BB*TT)
#define EPSV 1e-5f

typedef float f32x4 __attribute__((ext_vector_type(4)));
typedef short bf16x8 __attribute__((ext_vector_type(8)));

__device__ __forceinline__ float bf2f(unsigned short u) {
    union { unsigned int i; float f; } c; c.i = ((unsigned int)u) << 16; return c.f;
}
__device__ __forceinline__ unsigned short f2bf(float f) {
    union { float f; unsigned int i; } c; c.f = f;
    unsigned int x = c.i;
    return (unsigned short)((x + 0x7fffu + ((x >> 16) & 1u)) >> 16);  // RNE
}
__device__ __forceinline__ float cvt_in(const void* src, long long j, int isbf) {
    return isbf ? bf2f(((const unsigned short*)src)[j]) : ((const float*)src)[j];
}

// async global->LDS, 16 B per lane; LDS dest = wave-uniform base + lane*16
__device__ __forceinline__ void gl_lds16(const unsigned short* g, unsigned short* l) {
    __builtin_amdgcn_global_load_lds(
        (const __attribute__((address_space(1))) unsigned int*)g,
        (__attribute__((address_space(3))) unsigned int*)l,
        16, 0, 0);
}

// ---- dtype detection (fp32 vs bf16 input buffers) ----
__global__ void detect_kernel(const unsigned short* __restrict__ x, int* __restrict__ flag) {
    __shared__ int cnts[256];
    int cnt = 0;
    for (int i = threadIdx.x; i < 16384; i += 256) {
        unsigned short u = x[2 * i];
        int e = (u >> 7) & 0xFF;
        if (e >= 110 && e <= 140) cnt++;
    }
    cnts[threadIdx.x] = cnt;
    __syncthreads();
    for (int s = 128; s; s >>= 1) {
        if (threadIdx.x < s) cnts[threadIdx.x] += cnts[threadIdx.x + s];
        __syncthreads();
    }
    if (threadIdx.x == 0) flag[0] = (cnts[0] > 12000) ? 1 : 0;
}

// ---- converters ----
__global__ void load_f32_kernel(const void* __restrict__ src, float* __restrict__ dst,
                                const int* __restrict__ flag, int n) {
    int i = blockIdx.x * 256 + threadIdx.x;
    if (i >= n) return;
    dst[i] = cvt_in(src, i, flag[0]);
}
__global__ void load_small_kernel(const void* m_in, const void* aa, const void* af_,
                                  const void* bo, const void* b1, const void* b2,
                                  float* mf, float* embA, float* embF,
                                  float* boutf, float* b1f, float* b2f,
                                  const int* __restrict__ flag) {
    int i = blockIdx.x * 256 + threadIdx.x;
    int isbf = flag[0];
    if (i < 2048)        mf[i] = cvt_in(m_in, i, isbf);
    else if (i < 67584)  embA[i - 2048] = cvt_in(aa, i - 2048, isbf);
    else if (i < 133120) embF[i - 67584] = cvt_in(af_, i - 67584, isbf);
    else if (i < 137216) boutf[i - 133120] = cvt_in(bo, i - 133120, isbf);
    else if (i < 153600) b1f[i - 137216] = cvt_in(b1, i - 137216, isbf);
    else if (i < 157696) b2f[i - 153600] = cvt_in(b2, i - 153600, isbf);
}

// ---- per-layer fused weight transpose: dst(N,K) bf16 <- src(K,N) ----
__global__ __launch_bounds__(256)
void transpose_layer_kernel(const void* Wqkv, const void* Wo, const void* W1, const void* W2,
                            unsigned short* wq, unsigned short* wo,
                            unsigned short* w1, unsigned short* w2,
                            const int* __restrict__ flag,
                            long long o_qkv, long long o_o, long long o_1, long long o_2) {
    __shared__ float tile[32][33];
    int bid = blockIdx.x;
    const void* src; unsigned short* dst; long long off; int N, K, nt, kt;
    if (bid < 3072)      { int t = bid;        src = Wqkv; dst = wq; off = o_qkv; N = 3072; K = 1024; nt = t % 96;  kt = t / 96; }
    else if (bid < 4096) { int t = bid - 3072; src = Wo;   dst = wo; off = o_o;   N = 1024; K = 1024; nt = t % 32;  kt = t / 32; }
    else if (bid < 8192) { int t = bid - 4096; src = W1;   dst = w1; off = o_1;   N = 4096; K = 1024; nt = t % 128; kt = t / 128; }
    else                 { int t = bid - 8192; src = W2;   dst = w2; off = o_2;   N = 1024; K = 4096; nt = t % 32;  kt = t / 32; }
    int n0 = nt * 32, k0 = kt * 32;
    int r = threadIdx.x >> 5, c = threadIdx.x & 31;
    int isbf = flag[0];
    #pragma unroll
    for (int rr = 0; rr < 4; ++rr) {
        int k = k0 + r + rr * 8;
        tile[r + rr * 8][c] = cvt_in(src, off + (long long)k * N + n0 + c, isbf);
    }
    __syncthreads();
    #pragma unroll
    for (int rr = 0; rr < 4; ++rr) {
        int n = n0 + r + rr * 8;
        dst[(size_t)n * K + k0 + c] = f2bf(tile[c][r + rr * 8]);
    }
}

// ---- dual block reduction (blockDim.x == 256) ----
__device__ __forceinline__ void blk_sum2_256(float& a, float& b, float* red) {
    #pragma unroll
    for (int off = 32; off; off >>= 1) {
        a += __shfl_down(a, off, 64);
        b += __shfl_down(b, off, 64);
    }
    int tid = threadIdx.x;
    __syncthreads();
    if ((tid & 63) == 0) { red[tid >> 6] = a; red[4 + (tid >> 6)] = b; }
    __syncthreads();
    a = red[0] + red[1] + red[2] + red[3];
    b = red[4] + red[5] + red[6] + red[7];
}

// ---- AdaLN (single pass mean/var) ----
__global__ __launch_bounds__(256)
void adaln_kernel(const float* __restrict__ x,
                  const float* __restrict__ emb,
                  const int* __restrict__ lvl,
                  const float* __restrict__ mvec,
                  unsigned short* __restrict__ h) {
    __shared__ float red[8];
    int row = blockIdx.x;
    int b = row / TT;
    int tid = threadIdx.x;
    const float* xr = x + (size_t)row * D_MODEL;

    float s = 0.f, ss = 0.f;
    for (int j = tid; j < D_MODEL; j += 256) { float v = xr[j]; s += v; ss += v * v; }
    blk_sum2_256(s, ss, red);
    float mu = s * (1.0f / D_MODEL);
    float var = ss * (1.0f / D_MODEL) - mu * mu;
    float rstd = rsqrtf(var + EPSV);

    int lv = lvl[b];
    const float* g = emb + (size_t)lv * (2 * D_MODEL);
    float mval = mvec[row];
    unsigned short* hr = h + (size_t)row * D_MODEL;
    for (int j = tid; j < D_MODEL; j += 256) {
        float hn = (xr[j] - mu) * rstd;
        float h2 = 2.0f * (1.0f - 0.1f * hn) * hn;
        float o = __expf(g[j]) * h2 + g[D_MODEL + j];
        hr[j] = f2bf(o * mval);
    }
}

// ---- 8-wave MFMA GEMM (verified R5) ----
#define EPI_STORE 0
#define EPI_GELU  1
#define EPI_RESID 2
#define EPI_PART  3

template<int MI, int NI, int WR, int WC>
__global__ __launch_bounds__(512)
void gemm8_kernel(const unsigned short* __restrict__ A, int lda,
                  const unsigned short* __restrict__ BT, int ldb,
                  const float* __restrict__ bias,
                  unsigned short* __restrict__ outb,
                  const float* __restrict__ xin,
                  float* __restrict__ xout,
                  const float* __restrict__ mvec,
                  float* __restrict__ pbuf,
                  int M, int N, int K, int mode) {
    constexpr int BM = WR * MI * 16;
    constexpr int BN = WC * NI * 16;
    __shared__ __align__(16) unsigned short As[BM * 32];
    __shared__ __align__(16) unsigned short Bs[BN * 32];
    int tid = threadIdx.x;
    int wave = tid >> 6;
    int lane = tid & 63;
    int quad = lane >> 4;
    int l16  = lane & 15;
    int tileM = blockIdx.y * BM;
    int tileN = blockIdx.x * BN;
    int wm = (wave % WR) * MI * 16;
    int wn = (wave / WR) * NI * 16;

    f32x4 acc[MI][NI] = {};

    long long zoff = (long long)blockIdx.z * K;
    const unsigned short* Abase = A  + zoff + (size_t)(tileM + wave * 16 + (lane >> 2)) * lda + (lane & 3) * 8;
    const unsigned short* Bbase = BT + zoff + (size_t)(tileN + (wave % (BN / 16)) * 16 + (lane >> 2)) * ldb + (lane & 3) * 8;

    for (int k0 = 0; k0 < K; k0 += 32) {
        gl_lds16(Abase + k0, &As[wave * 512]);
        if (wave < BN / 16) gl_lds16(Bbase + k0, &Bs[wave * 512]);
        __syncthreads();

        bf16x8 af[MI], bf[NI];
        #pragma unroll
        for (int mi = 0; mi < MI; ++mi)
            af[mi] = *(const bf16x8*)(&As[(wm + mi * 16 + l16) * 32 + quad * 8]);
        #pragma unroll
        for (int ni = 0; ni < NI; ++ni)
            bf[ni] = *(const bf16x8*)(&Bs[(wn + ni * 16 + l16) * 32 + quad * 8]);
        #pragma unroll
        for (int mi = 0; mi < MI; ++mi)
            #pragma unroll
            for (int ni = 0; ni < NI; ++ni)
                acc[mi][ni] = __builtin_amdgcn_mfma_f32_16x16x32_bf16(af[mi], bf[ni], acc[mi][ni], 0, 0, 0);
        __syncthreads();
    }

    #pragma unroll
    for (int mi = 0; mi < MI; ++mi)
    #pragma unroll
    for (int ni = 0; ni < NI; ++ni) {
        #pragma unroll
        for (int r = 0; r < 4; ++r) {
            int row = tileM + wm + mi * 16 + quad * 4 + r;
            int col = tileN + wn + ni * 16 + l16;
            float v = acc[mi][ni][r];
            size_t idx = (size_t)row * N + col;
            if (mode == EPI_STORE) {
                outb[idx] = f2bf(v);
            } else if (mode == EPI_GELU) {
                v += bias[col];
                float gel = 0.5f * v * (1.0f + erff(v * 0.70710678118654752f));
                outb[idx] = f2bf(gel);
            } else if (mode == EPI_RESID) {
                v += bias[col];
                xout[idx] = (xin[idx] + v) * mvec[row];
            } else {
                pbuf[(size_t)blockIdx.z * M * N + idx] = v;
            }
        }
    }
}

// combine 2 split-K partials + bias + residual + mask; optional fused final store
__global__ void combine2_kernel(float* __restrict__ xf,
                                const float* __restrict__ pbuf,
                                const float* __restrict__ bias,
                                const float* __restrict__ mvec,
                                void* __restrict__ outp,
                                const int* __restrict__ flag, int n) {
    int i = blockIdx.x * 256 + threadIdx.x;
    if (i >= n) return;
    int row = i >> 10, col = i & 1023;
    float v = (xf[i] + pbuf[i] + pbuf[n + i] + bias[col]) * mvec[row];
    xf[i] = v;
    if (outp) {
        if (flag[0]) ((unsigned short*)outp)[i] = f2bf(v);
        else         ((float*)outp)[i] = v;
    }
}

// ---- split-j flash attention: 2 blocks per (qt,hd,b), j-tiles by parity ----
#define FA_DPAD 72

__global__ __launch_bounds__(256)
void fattn_split_kernel(const unsigned short* __restrict__ qkv,
                        float* __restrict__ Opart,   // [2][MM][1024] fp32 unnormalized
                        float* __restrict__ ml) {    // [2][MM][16][2] fp32 (m,l)
    __shared__ __align__(16) unsigned short Qs[64 * FA_DPAD];
    __shared__ __align__(16) unsigned short Ks[64 * FA_DPAD];
    __shared__ __align__(16) unsigned short Vs[64 * FA_DPAD];
    __shared__ __align__(16) unsigned short Ps[64 * FA_DPAD];

    int qt  = blockIdx.x;            // 0..15
    int hd  = blockIdx.y;
    int b   = blockIdx.z >> 1;
    int s   = blockIdx.z & 1;        // j-parity split
    int tid = threadIdx.x;
    int wave = tid >> 6;
    int lane = tid & 63;
    int quad = lane >> 4;
    int l16  = lane & 15;

    const unsigned short* base = qkv + (size_t)b * TT * 3072;

    {
        int r = tid >> 2, c = (tid & 3) * 16;
        const unsigned short* src = base + (size_t)(qt * 64 + r) * 3072 + hd * DH + c;
        *(uint4*)(&Qs[r * FA_DPAD + c])     = *(const uint4*)(src);
        *(uint4*)(&Qs[r * FA_DPAD + c + 8]) = *(const uint4*)(src + 8);
    }
    __syncthreads();

    bf16x8 aq[2];
    #pragma unroll
    for (int cc = 0; cc < 2; ++cc)
        aq[cc] = *(const bf16x8*)(&Qs[(wave * 16 + l16) * FA_DPAD + cc * 32 + quad * 8]);

    f32x4 Oacc[4] = {};
    float mstate[4], lstate[4];
    #pragma unroll
    for (int r = 0; r < 4; ++r) { mstate[r] = -1e30f; lstate[r] = 0.f; }

    for (int jt = s; jt <= qt; jt += 2) {
        __syncthreads();
        {
            int r = tid >> 2, c = (tid & 3) * 16;
            const unsigned short* src = base + (size_t)(jt * 64 + r) * 3072 + 1024 + hd * DH + c;
            *(uint4*)(&Ks[r * FA_DPAD + c])     = *(const uint4*)(src);
            *(uint4*)(&Ks[r * FA_DPAD + c + 8]) = *(const uint4*)(src + 8);
        }
        {
            int j = lane, c = wave * 16;
            const unsigned short* src = base + (size_t)(jt * 64 + j) * 3072 + 2048 + hd * DH + c;
            unsigned short tmp[16];
            *(uint4*)(tmp)     = *(const uint4*)(src);
            *(uint4*)(tmp + 8) = *(const uint4*)(src + 8);
            #pragma unroll
            for (int d = 0; d < 16; ++d) Vs[(c + d) * FA_DPAD + j] = tmp[d];
        }
        __syncthreads();

        f32x4 S[4] = {};
        #pragma unroll
        for (int t = 0; t < 4; ++t)
            #pragma unroll
            for (int cc = 0; cc < 2; ++cc) {
                bf16x8 bk = *(const bf16x8*)(&Ks[(t * 16 + l16) * FA_DPAD + cc * 32 + quad * 8]);
                S[t] = __builtin_amdgcn_mfma_f32_16x16x32_bf16(aq[cc], bk, S[t], 0, 0, 0);
            }

        int qrow0 = qt * 64 + wave * 16 + quad * 4;
        bool diag = (jt == qt);
        float mnew[4];
        #pragma unroll
        for (int r = 0; r < 4; ++r) {
            float v = -1e30f;
            #pragma unroll
            for (int t = 0; t < 4; ++t) {
                float sv = S[t][r] * 0.125f;
                if (diag) {
                    int j = jt * 64 + t * 16 + l16;
                    if (j > qrow0 + r) sv = -1e30f;
                }
                S[t][r] = sv;
                v = fmaxf(v, sv);
            }
            v = fmaxf(v, __shfl_xor(v, 1, 64));
            v = fmaxf(v, __shfl_xor(v, 2, 64));
            v = fmaxf(v, __shfl_xor(v, 4, 64));
            v = fmaxf(v, __shfl_xor(v, 8, 64));
            mnew[r] = fmaxf(mstate[r], v);
        }

        #pragma unroll
        for (int r = 0; r < 4; ++r) {
            float rs = 0.f;
            #pragma unroll
            for (int t = 0; t < 4; ++t) {
                float p = __expf(S[t][r] - mnew[r]);
                rs += p;
                Ps[(wave * 16 + quad * 4 + r) * FA_DPAD + t * 16 + l16] = f2bf(p);
            }
            rs += __shfl_xor(rs, 1, 64);
            rs += __shfl_xor(rs, 2, 64);
            rs += __shfl_xor(rs, 4, 64);
            rs += __shfl_xor(rs, 8, 64);
            float alpha = __expf(mstate[r] - mnew[r]);
            lstate[r] = alpha * lstate[r] + rs;
            mstate[r] = mnew[r];
            #pragma unroll
            for (int t = 0; t < 4; ++t) Oacc[t][r] *= alpha;
        }

        #pragma unroll
        for (int cc = 0; cc < 2; ++cc) {
            bf16x8 ap = *(const bf16x8*)(&Ps[(wave * 16 + l16) * FA_DPAD + cc * 32 + quad * 8]);
            #pragma unroll
            for (int t = 0; t < 4; ++t) {
                bf16x8 bv = *(const bf16x8*)(&Vs[(t * 16 + l16) * FA_DPAD + cc * 32 + quad * 8]);
                Oacc[t] = __builtin_amdgcn_mfma_f32_16x16x32_bf16(ap, bv, Oacc[t], 0, 0, 0);
            }
        }
    }

    // store unnormalized partials + (m,l)
    #pragma unroll
    for (int r = 0; r < 4; ++r) {
        int qi = qt * 64 + wave * 16 + quad * 4 + r;
        size_t row = (size_t)b * TT + qi;
        float* orow = Opart + (size_t)s * MM * D_MODEL + row * D_MODEL + hd * DH;
        #pragma unroll
        for (int t = 0; t < 4; ++t)
            orow[t * 16 + l16] = Oacc[t][r];
        if (l16 == 0) {
            float* mlp = ml + (((size_t)s * MM + row) * N_HEADS + hd) * 2;
            mlp[0] = mstate[r];
            mlp[1] = lstate[r];
        }
    }
}

// merge two j-splits -> normalized bf16 ob
__global__ void attn_merge_kernel(const float* __restrict__ Opart,
                                  const float* __restrict__ ml,
                                  unsigned short* __restrict__ ob) {
    int i = blockIdx.x * 256 + threadIdx.x;   // over MM*1024
    int row = i >> 10;
    int hd  = (i >> 6) & 15;
    const float* ml0 = ml + (((size_t)row) * N_HEADS + hd) * 2;
    const float* ml1 = ml + (((size_t)MM + row) * N_HEADS + hd) * 2;
    float m0 = ml0[0], l0 = ml0[1];
    float m1 = ml1[0], l1 = ml1[1];
    float M = fmaxf(m0, m1);
    float w0 = __expf(m0 - M), w1 = __expf(m1 - M);
    float den = w0 * l0 + w1 * l1;
    float num = w0 * Opart[i] + w1 * Opart[(size_t)MM * D_MODEL + i];
    ob[i] = f2bf(num / den);
}

// ---- workspace layout (bytes) ----
#define MB (1048576u)
#define WS_FLAG   0u
#define WS_MF     4096u
#define WS_EMBA   (WS_MF + 8192u)
#define WS_EMBF   (WS_EMBA + 262144u)
#define WS_BOUT   (WS_EMBF + 262144u)
#define WS_B1     (WS_BOUT + 16384u)
#define WS_B2     (WS_B1 + 65536u)
#define WS_XF     (1u*MB)    // 8 MB fp32 x
#define WS_H      (9u*MB)    // 4 MB bf16 h | ml (512 KB) after qkv GEMM | W2 partials (FFN)
#define WS_QKV    (13u*MB)   // 12 MB bf16
#define WS_OB     (25u*MB)   // 4 MB bf16
#define WS_PART   (9u*MB)    // 16 MB fp32 W2 split-K partials (FFN phase, h/qkv dead)
#define WS_ML     (9u*MB)    // 512 KB fp32 attn (m,l)   (attention phase, h dead)
#define WS_FF1    (29u*MB)   // 16 MB bf16 ff1 (FFN) | attn O-partials (attention phase)
#define WS_OPART  (29u*MB)
#define WS_WQKV   (45u*MB)   // 6 MB (3072 x 1024)
#define WS_WOUT   (51u*MB)   // 2 MB
#define WS_W1     (53u*MB)   // 8 MB (4096 x 1024)
#define WS_W2     (61u*MB)   // 8 MB (1024 x 4096)  end: 69 MB

extern "C" void kernel_launch(void* const* d_in, const int* in_sizes, int n_in,
                              void* d_out, int out_size, void* d_ws, size_t ws_size,
                              hipStream_t stream) {
    const void* x_in  = d_in[0];
    const void* m_in  = d_in[1];
    const int*  l_in  = (const int*)d_in[2];
    const void* Wqkv  = d_in[3];
    const void* Wout  = d_in[4];
    const void* boutp = d_in[5];
    const void* ada_a = d_in[6];
    const void* ada_f = d_in[7];
    const void* W1    = d_in[8];
    const void* b1    = d_in[9];
    const void* W2    = d_in[10];
    const void* b2    = d_in[11];

    char* ws = (char*)d_ws;
    int*            flag = (int*)(ws + WS_FLAG);
    float*          mf   = (float*)(ws + WS_MF);
    float*          embA = (float*)(ws + WS_EMBA);
    float*          embF = (float*)(ws + WS_EMBF);
    float*          boutf= (float*)(ws + WS_BOUT);
    float*          b1f  = (float*)(ws + WS_B1);
    float*          b2f  = (float*)(ws + WS_B2);
    float*          xf   = (float*)(ws + WS_XF);
    unsigned short* h    = (unsigned short*)(ws + WS_H);
    unsigned short* qkv  = (unsigned short*)(ws + WS_QKV);
    unsigned short* ob   = (unsigned short*)(ws + WS_OB);
    float*          part = (float*)(ws + WS_PART);
    float*          mlb  = (float*)(ws + WS_ML);
    float*          opart= (float*)(ws + WS_OPART);
    unsigned short* ff1  = (unsigned short*)(ws + WS_FF1);
    unsigned short* wqkvt= (unsigned short*)(ws + WS_WQKV);
    unsigned short* woutt= (unsigned short*)(ws + WS_WOUT);
    unsigned short* w1t  = (unsigned short*)(ws + WS_W1);
    unsigned short* w2t  = (unsigned short*)(ws + WS_W2);

    const int n = MM * D_MODEL;

    detect_kernel<<<1, 256, 0, stream>>>((const unsigned short*)x_in, flag);
    load_f32_kernel<<<n / 256, 256, 0, stream>>>(x_in, xf, flag, n);
    load_small_kernel<<<(157696 + 255) / 256, 256, 0, stream>>>(
        m_in, ada_a, ada_f, boutp, b1, b2, mf, embA, embF, boutf, b1f, b2f, flag);

    const long long nqkv = (long long)D_MODEL * 3 * D_MODEL;
    const long long nsq  = (long long)D_MODEL * D_MODEL;
    const long long nw1  = (long long)D_MODEL * 4 * D_MODEL;

    for (int i = 0; i < N_LAYERS; ++i) {
        transpose_layer_kernel<<<12288, 256, 0, stream>>>(
            Wqkv, Wout, W1, W2, wqkvt, woutt, w1t, w2t, flag,
            i * nqkv, i * nsq, i * nw1, i * nw1);

        // ---- attention sub-block ----
        adaln_kernel<<<MM, 256, 0, stream>>>(xf, embA + (size_t)i * N_LEVELS * 2 * D_MODEL, l_in, mf, h);
        gemm8_kernel<4,2,2,4><<<dim3(3072 / 128, MM / 128), 512, 0, stream>>>(
            h, 1024, wqkvt, 1024, nullptr, qkv, nullptr, nullptr, nullptr, nullptr,
            MM, 3072, 1024, EPI_STORE);
        fattn_split_kernel<<<dim3(TT / 64, N_HEADS, BB * 2), 256, 0, stream>>>(qkv, opart, mlb);
        attn_merge_kernel<<<n / 256, 256, 0, stream>>>(opart, mlb, ob);
        gemm8_kernel<2,2,4,2><<<dim3(1024 / 64, MM / 128), 512, 0, stream>>>(
            ob, 1024, woutt, 1024, boutf + (size_t)i * D_MODEL, nullptr, xf, xf, mf, nullptr,
            MM, 1024, 1024, EPI_RESID);
        // ---- FFN sub-block ----
        adaln_kernel<<<MM, 256, 0, stream>>>(xf, embF + (size_t)i * N_LEVELS * 2 * D_MODEL, l_in, mf, h);
        gemm8_kernel<4,2,2,4><<<dim3(4096 / 128, MM / 128), 512, 0, stream>>>(
            h, 1024, w1t, 1024, b1f + (size_t)i * 4 * D_MODEL, ff1, nullptr, nullptr, nullptr, nullptr,
            MM, 4096, 1024, EPI_GELU);
        gemm8_kernel<2,2,4,2><<<dim3(1024 / 64, MM / 128, 2), 512, 0, stream>>>(
            ff1, 4096, w2t, 4096, nullptr, nullptr, nullptr, nullptr, nullptr, part,
            MM, 1024, 2048, EPI_PART);
        combine2_kernel<<<n / 256, 256, 0, stream>>>(
            xf, part, b2f + (size_t)i * D_MODEL, mf,
            (i == N_LAYERS - 1) ? d_out : nullptr, flag, n);
    }
}